// Round 6
// baseline (2248.777 us; speedup 1.0000x reference)
//
#include <hip/hip_runtime.h>

typedef short bf16x8 __attribute__((ext_vector_type(8)));
typedef float f32x4 __attribute__((ext_vector_type(4)));

#define DN 128
#define DE 64
#define DEMB 128
#define DHID 256
#define SCALE 0.08838834764831845f  // 1/sqrt(128)

__device__ __forceinline__ ushort f2bf(float f) {
  unsigned u = __float_as_uint(f);
  return (ushort)((u + 0x7FFFu + ((u >> 16) & 1u)) >> 16);  // RNE
}
__device__ __forceinline__ float bf2f(ushort u) {
  return __uint_as_float((unsigned)u << 16);
}

// ---------- weight pack for GEMM1: W1[128][256] -> frag order, bf16 ----------
__global__ void k_prep1(const float* __restrict__ W1, ushort* __restrict__ Wp1) {
  int idx = blockIdx.x * 256 + threadIdx.x;
  if (idx >= 16 * 4 * 64 * 8) return;
  int j = idx & 7, lane = (idx >> 3) & 63, s = (idx >> 9) & 3, t = idx >> 11;
  int k = s * 32 + (lane >> 4) * 8 + j;
  int c = t * 16 + (lane & 15);
  Wp1[idx] = f2bf(W1[k * DHID + c]);
}

// ---------- weight pack for GEMM2: virtual Wcat[256][576] -> frag order, bf16 ----------
// col map: [0,128)=Wq*s | [128,384)=kv blocks of 8 (k[4g..+3],v[4g..+3]) | [384,512)=Wr | [512,576)=(Wq@We^T)*s
__global__ void k_prep2(const float* __restrict__ Wq, const float* __restrict__ Wk,
                        const float* __restrict__ Wv, const float* __restrict__ Wr,
                        const float* __restrict__ We, ushort* __restrict__ Wp2) {
  int idx = blockIdx.x * 256 + threadIdx.x;
  if (idx >= 36 * 8 * 64 * 8) return;
  int j = idx & 7, lane = (idx >> 3) & 63, s = (idx >> 9) & 7, t = idx >> 12;
  int k = s * 32 + (lane >> 4) * 8 + j;
  int c = t * 16 + (lane & 15);
  float v;
  if (c < 128)       v = Wq[k * DEMB + c] * SCALE;
  else if (c < 384) {
    int tt = c - 128, g = tt >> 3, r = tt & 7, col = 4 * g + (r & 3);
    v = (r < 4) ? Wk[k * DEMB + col] : Wv[k * DEMB + col];
  }
  else if (c < 512)  v = Wr[k * DEMB + (c - 384)];
  else {
    int cc = c - 512;
    float a = 0.f;
    for (int u = 0; u < DEMB; ++u) a += Wq[k * DEMB + u] * We[cc * DEMB + u];
    v = a * SCALE;
  }
  Wp2[idx] = f2bf(v);
}

__global__ void k_prep_b(const float* __restrict__ bq, const float* __restrict__ bk,
                         const float* __restrict__ bv, const float* __restrict__ br,
                         const float* __restrict__ be, const float* __restrict__ We,
                         float* __restrict__ bcat) {
  int j = blockIdx.x * 256 + threadIdx.x;
  if (j >= 576) return;
  float v;
  if (j < 128)       v = bq[j] * SCALE;
  else if (j < 384) {
    int tt = j - 128, g = tt >> 3, r = tt & 7, col = 4 * g + (r & 3);
    v = ((r < 4) ? bk[col] : bv[col]) + be[col];
  }
  else if (j < 512)  v = br[j - 384];
  else {
    int cc = j - 512;
    float a = 0.f;
    for (int u = 0; u < DEMB; ++u) a += bq[u] * We[cc * DEMB + u];
    v = a * SCALE;
  }
  bcat[j] = v;
}

// ---------- CSR build ----------
__global__ void k_deg(const int* __restrict__ ei, int* __restrict__ degi, int nE) {
  int e = blockIdx.x * 256 + threadIdx.x;
  if (e < nE) atomicAdd(&degi[ei[nE + e]], 1);
}

__global__ void k_dinv(const int* __restrict__ degi, float* __restrict__ dinv, int nN) {
  int n = blockIdx.x * 256 + threadIdx.x;
  if (n < nN) dinv[n] = rsqrtf(1.0f + (float)degi[n]);
}

// wave-based single-block exclusive scan (3 barriers/tile)
__global__ __launch_bounds__(1024) void k_scan(const int* __restrict__ degi,
                                               int* __restrict__ row_ptr, int n) {
  __shared__ int wsum[16];
  __shared__ int carry_s;
  int lane = threadIdx.x & 63, wid = threadIdx.x >> 6;
  if (threadIdx.x == 0) carry_s = 0;
  __syncthreads();
  for (int base = 0; base < n; base += 1024) {
    int i = base + threadIdx.x;
    int v = (i < n) ? degi[i] : 0;
    int sc = v;
    #pragma unroll
    for (int off = 1; off < 64; off <<= 1) {
      int t = __shfl_up(sc, off);
      if (lane >= off) sc += t;
    }
    if (lane == 63) wsum[wid] = sc;
    int carry0 = carry_s;
    __syncthreads();
    if (wid == 0) {
      int w = (lane < 16) ? wsum[lane] : 0;
      int swc = w;
      #pragma unroll
      for (int off = 1; off < 16; off <<= 1) {
        int t = __shfl_up(swc, off);
        if (lane >= off) swc += t;
      }
      if (lane < 16) wsum[lane] = swc - w;    // exclusive wave offsets
      if (lane == 15) carry_s = carry0 + swc; // running total
    }
    __syncthreads();
    if (i < n) row_ptr[i] = carry0 + wsum[wid] + sc - v;
    __syncthreads();
  }
  if (threadIdx.x == 0) row_ptr[n] = carry_s;
}

__global__ void k_scatter(const int* __restrict__ ei, const int* __restrict__ row_ptr,
                          int* __restrict__ cursor, int* __restrict__ csr_src,
                          int* __restrict__ csr_eid, int nE) {
  int e = blockIdx.x * 256 + threadIdx.x;
  if (e >= nE) return;
  int dst = ei[nE + e];
  int pos = row_ptr[dst] + atomicAdd(&cursor[dst], 1);
  csr_src[pos] = ei[e];
  csr_eid[pos] = e;
}

// chunk table: one entry per (node, 16-edge chunk); order arbitrary (atomic)
__global__ void k_chunkfill(const int* __restrict__ row_ptr, int* __restrict__ ctr,
                            int2* __restrict__ chunk_nb, int nN) {
  int n = blockIdx.x * 256 + threadIdx.x;
  if (n >= nN) return;
  int beg = row_ptr[n], end = row_ptr[n + 1];
  int cc = (end - beg + 15) >> 4;
  if (cc == 0) return;
  int pos = atomicAdd(ctr, cc);
  for (int j = 0; j < cc; ++j)
    chunk_nb[pos + j] = make_int2(n, beg + 16 * j);
}

// ---------- permute+convert edge_attr into CSR order (bf16) ----------
__global__ __launch_bounds__(256) void k_eaperm(const float* __restrict__ ea,
                                                const int* __restrict__ csr_eid,
                                                ushort* __restrict__ eaP, int nE) {
  int lane = threadIdx.x & 63;
  int wv = (blockIdx.x * 256 + threadIdx.x) >> 6;
  int nWaves = gridDim.x * 4;
  int grp = lane >> 5, l5 = lane & 31;
  for (int base = wv * 16; base < nE; base += nWaves * 16) {
    int idx = base + (lane & 15);
    int eidv = csr_eid[idx < nE ? idx : nE - 1];
    #pragma unroll
    for (int j = 0; j < 8; ++j) {
      int pos = base + 2 * j + grp;
      int eid = __shfl(eidv, 2 * j + grp);
      float2 v = *(const float2*)&ea[(size_t)eid * DE + l5 * 2];
      if (pos < nE) {
        ushort2 o; o.x = f2bf(v.x); o.y = f2bf(v.y);
        *(ushort2*)&eaP[(size_t)pos * DE + l5 * 2] = o;
      }
    }
  }
}

// ---------- GEMM1 (MFMA bf16): xwsb[n][256] = bf16( (x @ W1) * dinv[n] ) ----------
__global__ __launch_bounds__(256) void k_gemm1(const float* __restrict__ x,
                                               const ushort* __restrict__ Wp1,
                                               const float* __restrict__ dinv,
                                               ushort* __restrict__ xwsb, int nN) {
  int lane = threadIdx.x & 63, wave = threadIdx.x >> 6;
  int l15 = lane & 15, lh = lane >> 4;
  int m0 = blockIdx.x * 16;
  int rowa = m0 + l15; if (rowa >= nN) rowa = nN - 1;
  f32x4 acc[4] = {};
  for (int s = 0; s < 4; ++s) {
    const float* ap = &x[(size_t)rowa * DN + s * 32 + lh * 8];
    float4 a0 = *(const float4*)ap;
    float4 a1 = *(const float4*)(ap + 4);
    bf16x8 af;
    af[0] = (short)f2bf(a0.x); af[1] = (short)f2bf(a0.y);
    af[2] = (short)f2bf(a0.z); af[3] = (short)f2bf(a0.w);
    af[4] = (short)f2bf(a1.x); af[5] = (short)f2bf(a1.y);
    af[6] = (short)f2bf(a1.z); af[7] = (short)f2bf(a1.w);
    #pragma unroll
    for (int tt = 0; tt < 4; ++tt) {
      int t = wave * 4 + tt;
      bf16x8 bf = *(const bf16x8*)&Wp1[((t * 4 + s) * 64 + lane) * 8];
      acc[tt] = __builtin_amdgcn_mfma_f32_16x16x32_bf16(af, bf, acc[tt], 0, 0, 0);
    }
  }
  #pragma unroll
  for (int tt = 0; tt < 4; ++tt) {
    int c = (wave * 4 + tt) * 16 + l15;
    #pragma unroll
    for (int r = 0; r < 4; ++r) {
      int row = m0 + lh * 4 + r;
      if (row < nN) xwsb[(size_t)row * DHID + c] = f2bf(acc[tt][r] * dinv[row]);
    }
  }
}

// ---------- GEMM2 (MFMA bf16): qrb (bf16 q|hr|wqe) + kvb (bf16 interleaved) ----------
__global__ __launch_bounds__(256) void k_gemm2(const ushort* __restrict__ hb,
                                               const ushort* __restrict__ Wp2,
                                               const float* __restrict__ bcat,
                                               ushort* __restrict__ qrb,
                                               ushort* __restrict__ kvb, int nN) {
  int lane = threadIdx.x & 63, wave = threadIdx.x >> 6;
  int l15 = lane & 15, lh = lane >> 4;
  int m0 = blockIdx.x * 16;
  int rowa = m0 + l15; if (rowa >= nN) rowa = nN - 1;
  f32x4 acc[9] = {};
  for (int s = 0; s < 8; ++s) {
    bf16x8 af = *(const bf16x8*)&hb[(size_t)rowa * DHID + s * 32 + lh * 8];
    #pragma unroll
    for (int tt = 0; tt < 9; ++tt) {
      int t = wave * 9 + tt;
      bf16x8 bf = *(const bf16x8*)&Wp2[((t * 8 + s) * 64 + lane) * 8];
      acc[tt] = __builtin_amdgcn_mfma_f32_16x16x32_bf16(af, bf, acc[tt], 0, 0, 0);
    }
  }
  #pragma unroll
  for (int tt = 0; tt < 9; ++tt) {
    int c = (wave * 9 + tt) * 16 + l15;
    float bc = bcat[c];
    #pragma unroll
    for (int r = 0; r < 4; ++r) {
      int row = m0 + lh * 4 + r;
      if (row >= nN) continue;
      float val = acc[tt][r] + bc;
      if (c < 128)      qrb[(size_t)row * 320 + c] = f2bf(val);
      else if (c < 384) kvb[(size_t)row * 256 + (c - 128)] = f2bf(val);
      else if (c < 512) qrb[(size_t)row * 320 + 128 + (c - 384)] = f2bf(val);
      else              qrb[(size_t)row * 320 + 256 + (c - 512)] = f2bf(val);
    }
  }
}

// ---------- GCN aggregate: one wave per 16-edge chunk, atomic f32 partials ----------
__global__ __launch_bounds__(256) void k_gcnchunk(const ushort* __restrict__ xwsb,
                                                  const int* __restrict__ csr_src,
                                                  const int* __restrict__ row_ptr,
                                                  const int2* __restrict__ chunk_nb,
                                                  const int* __restrict__ chunkctr,
                                                  float* __restrict__ gacc) {
  int wid = (blockIdx.x * 256 + threadIdx.x) >> 6;
  if (wid >= *chunkctr) return;
  int lane = threadIdx.x & 63, grp = lane >> 5, l5 = lane & 31;
  int2 nb = chunk_nb[wid];
  int n = nb.x, beg = nb.y;
  int cnt = row_ptr[n + 1] - beg; if (cnt > 16) cnt = 16;
  int li = lane & 15; if (li >= cnt) li = cnt - 1;
  int srcv = csr_src[beg + li];
  uint4 xv[8];
  #pragma unroll
  for (int j = 0; j < 8; ++j) {
    int sj = __shfl(srcv, 2 * j + grp);
    xv[j] = *(const uint4*)&xwsb[(size_t)sj * DHID + l5 * 8];
  }
  float acc[8] = {};
  #pragma unroll
  for (int j = 0; j < 8; ++j) {
    float w = (2 * j + grp < cnt) ? 1.f : 0.f;
    unsigned q[4] = {xv[j].x, xv[j].y, xv[j].z, xv[j].w};
    #pragma unroll
    for (int d = 0; d < 4; ++d) {
      acc[2*d]   = fmaf(w, __uint_as_float(q[d] << 16), acc[2*d]);
      acc[2*d+1] = fmaf(w, __uint_as_float(q[d] & 0xFFFF0000u), acc[2*d+1]);
    }
  }
  #pragma unroll
  for (int d = 0; d < 8; ++d) acc[d] += __shfl_xor(acc[d], 32);
  if (grp == 0) {
    #pragma unroll
    for (int d = 0; d < 8; ++d)
      atomicAdd(&gacc[(size_t)n * DHID + l5 * 8 + d], acc[d]);
  }
}

// ---------- GCN finalize: h = relu((gacc + self)*dinv + b1), 2 nodes/wave ----------
__global__ __launch_bounds__(256) void k_gcnfin(const float* __restrict__ gacc,
                                                const ushort* __restrict__ xwsb,
                                                const float* __restrict__ dinv,
                                                const float* __restrict__ b1,
                                                ushort* __restrict__ hb, int nN) {
  int lane = threadIdx.x & 63, grp = lane >> 5, l5 = lane & 31;
  int n = blockIdx.x * 8 + (threadIdx.x >> 6) * 2 + grp;
  if (n >= nN) return;
  float dn = dinv[n];
  uint4 sv = *(const uint4*)&xwsb[(size_t)n * DHID + l5 * 8];
  unsigned sq[4] = {sv.x, sv.y, sv.z, sv.w};
  float4 g0 = *(const float4*)&gacc[(size_t)n * DHID + l5 * 8];
  float4 g1 = *(const float4*)&gacc[(size_t)n * DHID + l5 * 8 + 4];
  float ga[8] = {g0.x, g0.y, g0.z, g0.w, g1.x, g1.y, g1.z, g1.w};
  float4 bb0 = *(const float4*)&b1[l5 * 8];
  float4 bb1 = *(const float4*)&b1[l5 * 8 + 4];
  float bbs[8] = {bb0.x, bb0.y, bb0.z, bb0.w, bb1.x, bb1.y, bb1.z, bb1.w};
  unsigned ov[4];
  #pragma unroll
  for (int d = 0; d < 4; ++d) {
    float lo = __uint_as_float(sq[d] << 16);
    float hi = __uint_as_float(sq[d] & 0xFFFF0000u);
    float v0 = fmaxf((ga[2*d]   + lo) * dn + bbs[2*d],   0.f);
    float v1 = fmaxf((ga[2*d+1] + hi) * dn + bbs[2*d+1], 0.f);
    ov[d] = (unsigned)f2bf(v0) | ((unsigned)f2bf(v1) << 16);
  }
  uint4 o = {ov[0], ov[1], ov[2], ov[3]};
  *(uint4*)&hb[(size_t)n * DHID + l5 * 8] = o;
}

// ---------- attention chunk: one wave per 16-edge chunk; no-max softmax partials ----------
template<int EAP>
__global__ __launch_bounds__(256) void k_attnchunk(const ushort* __restrict__ qrb,
                                                   const ushort* __restrict__ kvb,
                                                   const ushort* __restrict__ eaP,
                                                   const float* __restrict__ ea32,
                                                   const int* __restrict__ csr_src,
                                                   const int* __restrict__ csr_eid,
                                                   const int* __restrict__ row_ptr,
                                                   const int2* __restrict__ chunk_nb,
                                                   const int* __restrict__ chunkctr,
                                                   float* __restrict__ sden,
                                                   float* __restrict__ vacc,
                                                   float* __restrict__ eacc) {
  int wid = (blockIdx.x * 256 + threadIdx.x) >> 6;
  if (wid >= *chunkctr) return;
  int lane = threadIdx.x & 63, grp = lane >> 5, l5 = lane & 31;
  int2 nb = chunk_nb[wid];
  int n = nb.x, beg = nb.y;
  int cnt = row_ptr[n + 1] - beg; if (cnt > 16) cnt = 16;
  int li = lane & 15; if (li >= cnt) li = cnt - 1;
  int srcv = csr_src[beg + li];
  int eidv = 0;
  if (!EAP) eidv = csr_eid[beg + li];
  const ushort* qb = &qrb[(size_t)n * 320];
  ushort4 qv = *(const ushort4*)&qb[l5 * 4];
  ushort2 wv = *(const ushort2*)&qb[256 + l5 * 2];
  float q0 = bf2f(qv.x), q1 = bf2f(qv.y), q2 = bf2f(qv.z), q3 = bf2f(qv.w);
  float we0 = bf2f(wv.x), we1 = bf2f(wv.y);
  uint4 kv[8]; float2 eav[8];
  #pragma unroll
  for (int j = 0; j < 8; ++j) {
    int sj = __shfl(srcv, 2 * j + grp);
    kv[j] = *(const uint4*)&kvb[(size_t)sj * DHID + l5 * 8];
    if (EAP) {
      int pj = 2 * j + grp; if (pj >= cnt) pj = cnt - 1;
      ushort2 e2 = *(const ushort2*)&eaP[((size_t)(beg + pj)) * DE + l5 * 2];
      eav[j].x = bf2f(e2.x); eav[j].y = bf2f(e2.y);
    } else {
      int ej = __shfl(eidv, 2 * j + grp);
      eav[j] = *(const float2*)&ea32[(size_t)ej * DE + l5 * 2];
    }
  }
  float ps = 0.f;
  float4 pv = {0, 0, 0, 0};
  float2 pe = {0, 0};
  #pragma unroll
  for (int j = 0; j < 8; ++j) {
    float k0 = __uint_as_float(kv[j].x << 16);
    float k1 = __uint_as_float(kv[j].x & 0xFFFF0000u);
    float k2 = __uint_as_float(kv[j].y << 16);
    float k3 = __uint_as_float(kv[j].y & 0xFFFF0000u);
    float part = q0*k0 + q1*k1 + q2*k2 + q3*k3 + we0*eav[j].x + we1*eav[j].y;
    #pragma unroll
    for (int off = 1; off < 32; off <<= 1) part += __shfl_xor(part, off);
    float p = (2 * j + grp < cnt) ? __expf(part) : 0.f;
    ps += p;
    pv.x += p * __uint_as_float(kv[j].z << 16);
    pv.y += p * __uint_as_float(kv[j].z & 0xFFFF0000u);
    pv.z += p * __uint_as_float(kv[j].w << 16);
    pv.w += p * __uint_as_float(kv[j].w & 0xFFFF0000u);
    pe.x += p * eav[j].x;
    pe.y += p * eav[j].y;
  }
  ps   += __shfl_xor(ps, 32);
  pv.x += __shfl_xor(pv.x, 32); pv.y += __shfl_xor(pv.y, 32);
  pv.z += __shfl_xor(pv.z, 32); pv.w += __shfl_xor(pv.w, 32);
  pe.x += __shfl_xor(pe.x, 32); pe.y += __shfl_xor(pe.y, 32);
  if (grp == 0) {
    atomicAdd(&vacc[(size_t)n * 128 + l5 * 4 + 0], pv.x);
    atomicAdd(&vacc[(size_t)n * 128 + l5 * 4 + 1], pv.y);
    atomicAdd(&vacc[(size_t)n * 128 + l5 * 4 + 2], pv.z);
    atomicAdd(&vacc[(size_t)n * 128 + l5 * 4 + 3], pv.w);
    atomicAdd(&eacc[(size_t)n * 64 + l5 * 2 + 0], pe.x);
    atomicAdd(&eacc[(size_t)n * 64 + l5 * 2 + 1], pe.y);
    if (l5 == 0) atomicAdd(&sden[n], ps);
  }
}

// ---------- finalize: divide, We matvec, +hr, LN, ReLU, pool; 2 nodes/wave ----------
__global__ __launch_bounds__(256) void k_fin(const ushort* __restrict__ qrb,
                                             const float* __restrict__ sden,
                                             const float* __restrict__ vacc,
                                             const float* __restrict__ eacc,
                                             const float* __restrict__ We,
                                             const int* __restrict__ batch,
                                             const float* __restrict__ gamma,
                                             const float* __restrict__ beta,
                                             float* __restrict__ pool,
                                             float* __restrict__ cnt, int nN) {
  int lane = threadIdx.x & 63, grp = lane >> 5, l5 = lane & 31;
  int n = blockIdx.x * 8 + (threadIdx.x >> 6) * 2 + grp;
  if (n >= nN) return;
  float s = sden[n];
  float inv = (s > 0.f) ? 1.f / s : 0.f;
  float4 v4 = *(const float4*)&vacc[(size_t)n * 128 + l5 * 4];
  float2 e2 = *(const float2*)&eacc[(size_t)n * 64 + l5 * 2];
  float4 o4;
  o4.x = v4.x * inv; o4.y = v4.y * inv; o4.z = v4.z * inv; o4.w = v4.w * inv;
  float ex = e2.x * inv, ey = e2.y * inv;
  int gb = grp << 5;
  #pragma unroll 8
  for (int c = 0; c < 64; c += 2) {
    float e0 = __shfl(ex, (c >> 1) + gb);
    float e1 = __shfl(ey, (c >> 1) + gb);
    float4 w0 = *(const float4*)&We[c * DEMB + l5 * 4];
    float4 w1 = *(const float4*)&We[(c + 1) * DEMB + l5 * 4];
    o4.x += e0 * w0.x + e1 * w1.x;
    o4.y += e0 * w0.y + e1 * w1.y;
    o4.z += e0 * w0.z + e1 * w1.z;
    o4.w += e0 * w0.w + e1 * w1.w;
  }
  ushort4 hv = *(const ushort4*)&qrb[(size_t)n * 320 + 128 + l5 * 4];
  o4.x += bf2f(hv.x); o4.y += bf2f(hv.y); o4.z += bf2f(hv.z); o4.w += bf2f(hv.w);
  float s1 = o4.x + o4.y + o4.z + o4.w;
  float sq = o4.x*o4.x + o4.y*o4.y + o4.z*o4.z + o4.w*o4.w;
  #pragma unroll
  for (int off = 1; off < 32; off <<= 1) {
    s1 += __shfl_xor(s1, off);
    sq += __shfl_xor(sq, off);
  }
  float mu = s1 * (1.f / 128.f);
  float var = sq * (1.f / 128.f) - mu * mu;
  float rstd = rsqrtf(var + 1e-5f);
  float4 g4 = *(const float4*)&gamma[l5 * 4];
  float4 b4 = *(const float4*)&beta[l5 * 4];
  int b = batch[n];
  atomicAdd(&pool[b * DEMB + l5 * 4 + 0], fmaxf((o4.x - mu) * rstd * g4.x + b4.x, 0.f));
  atomicAdd(&pool[b * DEMB + l5 * 4 + 1], fmaxf((o4.y - mu) * rstd * g4.y + b4.y, 0.f));
  atomicAdd(&pool[b * DEMB + l5 * 4 + 2], fmaxf((o4.z - mu) * rstd * g4.z + b4.z, 0.f));
  atomicAdd(&pool[b * DEMB + l5 * 4 + 3], fmaxf((o4.w - mu) * rstd * g4.w + b4.w, 0.f));
  if (l5 == 0) atomicAdd(&cnt[b], 1.f);
}

__global__ void k_final(const float* __restrict__ pool, const float* __restrict__ cnt,
                        float* __restrict__ out, int total) {
  int i = blockIdx.x * 256 + threadIdx.x;
  if (i < total) out[i] = pool[i] / fmaxf(cnt[i >> 7], 1.f);
}

extern "C" void kernel_launch(void* const* d_in, const int* in_sizes, int n_in,
                              void* d_out, int out_size, void* d_ws, size_t ws_size,
                              hipStream_t stream) {
  const float* x         = (const float*)d_in[0];
  const float* edge_attr = (const float*)d_in[1];
  const int*   edge_index= (const int*)d_in[2];
  const int*   batch     = (const int*)d_in[3];
  const float* W1 = (const float*)d_in[4];
  const float* b1 = (const float*)d_in[5];
  const float* Wq = (const float*)d_in[6];  const float* bq = (const float*)d_in[7];
  const float* Wk = (const float*)d_in[8];  const float* bk = (const float*)d_in[9];
  const float* Wv = (const float*)d_in[10]; const float* bv = (const float*)d_in[11];
  const float* We = (const float*)d_in[12]; const float* be = (const float*)d_in[13];
  const float* Wr = (const float*)d_in[14]; const float* br = (const float*)d_in[15];
  const float* gamma = (const float*)d_in[16];
  const float* beta  = (const float*)d_in[17];
  float* out = (float*)d_out;

  const int nN = in_sizes[0] / DN;       // 50000
  const int nE = in_sizes[1] / DE;       // 1600000
  const int CMAX = nE / 16 + nN;         // upper bound on chunk count

  char* p = (char*)d_ws;
  auto alloc = [&](size_t bytes) -> void* {
    void* r = (void*)p;
    p += (bytes + 255) & ~(size_t)255;
    return r;
  };
  // ---- zeroed region ----
  int*   degi     = (int*)  alloc((size_t)nN * 4);
  int*   cursor   = (int*)  alloc((size_t)nN * 4);
  int*   chunkctr = (int*)  alloc(4);
  float* pool     = (float*)alloc((size_t)out_size * 4);
  float* cnt      = (float*)alloc(64 * 4);
  float* sden     = (float*)alloc((size_t)nN * 4);
  float* vacc     = (float*)alloc((size_t)nN * 128 * 4);
  float* eacc     = (float*)alloc((size_t)nN * 64 * 4);
  // union: gacc (f32[nN][256], live gemm1..gcnfin) then qrb (bf16[nN][320], live gemm2..fin)
  void*  uni      = alloc((size_t)nN * 1024);
  float*  gacc = (float*)uni;
  ushort* qrb  = (ushort*)uni;
  size_t zero_bytes = (size_t)(p - (char*)d_ws);
  // ---- non-zeroed ----
  int*    row_ptr  = (int*)   alloc((size_t)(nN + 1) * 4);
  float*  dinv     = (float*) alloc((size_t)nN * 4);
  int*    csr_src  = (int*)   alloc((size_t)nE * 4);
  int*    csr_eid  = (int*)   alloc((size_t)nE * 4);
  int2*   chunk_nb = (int2*)  alloc((size_t)CMAX * 8);
  ushort* Wp1      = (ushort*)alloc((size_t)16 * 4 * 64 * 8 * 2);
  ushort* Wp2      = (ushort*)alloc((size_t)36 * 8 * 64 * 8 * 2);
  float*  bcat     = (float*) alloc(576 * 4);
  ushort* hb       = (ushort*)alloc((size_t)nN * DHID * 2);
  ushort* xwsb     = (ushort*)alloc((size_t)nN * DHID * 2);  // aliased: xws then kv
  ushort* kvb      = xwsb;
  size_t base_required = (size_t)(p - (char*)d_ws);
  if (ws_size < base_required) return;
  // optional: permuted bf16 edge_attr (CSR order) — use only if workspace allows
  ushort* eaP = nullptr;
  size_t eap_bytes = (((size_t)nE * DE * 2) + 255) & ~(size_t)255;
  if (ws_size >= base_required + eap_bytes) eaP = (ushort*)alloc(eap_bytes);

  hipMemsetAsync(d_ws, 0, zero_bytes, stream);

  k_prep1<<<128, 256, 0, stream>>>(W1, Wp1);
  k_prep2<<<576, 256, 0, stream>>>(Wq, Wk, Wv, Wr, We, Wp2);
  k_prep_b<<<3, 256, 0, stream>>>(bq, bk, bv, br, be, We, bcat);
  k_deg<<<(nE + 255) / 256, 256, 0, stream>>>(edge_index, degi, nE);
  k_dinv<<<(nN + 255) / 256, 256, 0, stream>>>(degi, dinv, nN);
  k_scan<<<1, 1024, 0, stream>>>(degi, row_ptr, nN);
  k_scatter<<<(nE + 255) / 256, 256, 0, stream>>>(edge_index, row_ptr, cursor,
                                                  csr_src, csr_eid, nE);
  k_chunkfill<<<(nN + 255) / 256, 256, 0, stream>>>(row_ptr, chunkctr, chunk_nb, nN);
  if (eaP)
    k_eaperm<<<2048, 256, 0, stream>>>(edge_attr, csr_eid, eaP, nE);
  k_gemm1<<<(nN + 15) / 16, 256, 0, stream>>>(x, Wp1, dinv, xwsb, nN);
  {
    int blocks = (CMAX + 3) / 4;
    k_gcnchunk<<<blocks, 256, 0, stream>>>(xwsb, csr_src, row_ptr, chunk_nb,
                                           chunkctr, gacc);
  }
  k_gcnfin<<<(nN + 7) / 8, 256, 0, stream>>>(gacc, xwsb, dinv, b1, hb, nN);
  k_gemm2<<<(nN + 15) / 16, 256, 0, stream>>>(hb, Wp2, bcat, qrb, kvb, nN);
  {
    int blocks = (CMAX + 3) / 4;
    if (eaP)
      k_attnchunk<1><<<blocks, 256, 0, stream>>>(qrb, kvb, eaP, edge_attr, csr_src,
                                                 csr_eid, row_ptr, chunk_nb, chunkctr,
                                                 sden, vacc, eacc);
    else
      k_attnchunk<0><<<blocks, 256, 0, stream>>>(qrb, kvb, eaP, edge_attr, csr_src,
                                                 csr_eid, row_ptr, chunk_nb, chunkctr,
                                                 sden, vacc, eacc);
  }
  k_fin<<<(nN + 7) / 8, 256, 0, stream>>>(qrb, sden, vacc, eacc, We, batch,
                                          gamma, beta, pool, cnt, nN);
  k_final<<<(out_size + 255) / 256, 256, 0, stream>>>(pool, cnt, out, out_size);
}

// Round 7
// 1293.362 us; speedup vs baseline: 1.7387x; 1.7387x over previous
//
#include <hip/hip_runtime.h>

typedef short bf16x8 __attribute__((ext_vector_type(8)));
typedef float f32x4 __attribute__((ext_vector_type(4)));

#define DN 128
#define DE 64
#define DEMB 128
#define DHID 256
#define SCALE 0.08838834764831845f  // 1/sqrt(128)

__device__ __forceinline__ ushort f2bf(float f) {
  unsigned u = __float_as_uint(f);
  return (ushort)((u + 0x7FFFu + ((u >> 16) & 1u)) >> 16);  // RNE
}
__device__ __forceinline__ float bf2f(ushort u) {
  return __uint_as_float((unsigned)u << 16);
}

// ---------- weight pack for GEMM1: W1[128][256] -> frag order, bf16 ----------
__global__ void k_prep1(const float* __restrict__ W1, ushort* __restrict__ Wp1) {
  int idx = blockIdx.x * 256 + threadIdx.x;
  if (idx >= 16 * 4 * 64 * 8) return;
  int j = idx & 7, lane = (idx >> 3) & 63, s = (idx >> 9) & 3, t = idx >> 11;
  int k = s * 32 + (lane >> 4) * 8 + j;
  int c = t * 16 + (lane & 15);
  Wp1[idx] = f2bf(W1[k * DHID + c]);
}

// ---------- weight pack for GEMM2: virtual Wcat[256][576] -> frag order, bf16 ----------
// col map: [0,128)=Wq*s | [128,384)=kv blocks of 8 (k[4g..+3],v[4g..+3]) | [384,512)=Wr | [512,576)=(Wq@We^T)*s
__global__ void k_prep2(const float* __restrict__ Wq, const float* __restrict__ Wk,
                        const float* __restrict__ Wv, const float* __restrict__ Wr,
                        const float* __restrict__ We, ushort* __restrict__ Wp2) {
  int idx = blockIdx.x * 256 + threadIdx.x;
  if (idx >= 36 * 8 * 64 * 8) return;
  int j = idx & 7, lane = (idx >> 3) & 63, s = (idx >> 9) & 7, t = idx >> 12;
  int k = s * 32 + (lane >> 4) * 8 + j;
  int c = t * 16 + (lane & 15);
  float v;
  if (c < 128)       v = Wq[k * DEMB + c] * SCALE;
  else if (c < 384) {
    int tt = c - 128, g = tt >> 3, r = tt & 7, col = 4 * g + (r & 3);
    v = (r < 4) ? Wk[k * DEMB + col] : Wv[k * DEMB + col];
  }
  else if (c < 512)  v = Wr[k * DEMB + (c - 384)];
  else {
    int cc = c - 512;
    float a = 0.f;
    for (int u = 0; u < DEMB; ++u) a += Wq[k * DEMB + u] * We[cc * DEMB + u];
    v = a * SCALE;
  }
  Wp2[idx] = f2bf(v);
}

__global__ void k_prep_b(const float* __restrict__ bq, const float* __restrict__ bk,
                         const float* __restrict__ bv, const float* __restrict__ br,
                         const float* __restrict__ be, const float* __restrict__ We,
                         float* __restrict__ bcat) {
  int j = blockIdx.x * 256 + threadIdx.x;
  if (j >= 576) return;
  float v;
  if (j < 128)       v = bq[j] * SCALE;
  else if (j < 384) {
    int tt = j - 128, g = tt >> 3, r = tt & 7, col = 4 * g + (r & 3);
    v = ((r < 4) ? bk[col] : bv[col]) + be[col];
  }
  else if (j < 512)  v = br[j - 384];
  else {
    int cc = j - 512;
    float a = 0.f;
    for (int u = 0; u < DEMB; ++u) a += bq[u] * We[cc * DEMB + u];
    v = a * SCALE;
  }
  bcat[j] = v;
}

// ---------- CSR build ----------
__global__ void k_deg(const int* __restrict__ ei, int* __restrict__ degi, int nE) {
  int e = blockIdx.x * 256 + threadIdx.x;
  if (e < nE) atomicAdd(&degi[ei[nE + e]], 1);
}

__global__ void k_dinv(const int* __restrict__ degi, float* __restrict__ dinv, int nN) {
  int n = blockIdx.x * 256 + threadIdx.x;
  if (n < nN) dinv[n] = rsqrtf(1.0f + (float)degi[n]);
}

// wave-based single-block exclusive scan
__global__ __launch_bounds__(1024) void k_scan(const int* __restrict__ degi,
                                               int* __restrict__ row_ptr, int n) {
  __shared__ int wsum[16];
  __shared__ int carry_s;
  int lane = threadIdx.x & 63, wid = threadIdx.x >> 6;
  if (threadIdx.x == 0) carry_s = 0;
  __syncthreads();
  for (int base = 0; base < n; base += 1024) {
    int i = base + threadIdx.x;
    int v = (i < n) ? degi[i] : 0;
    int sc = v;
    #pragma unroll
    for (int off = 1; off < 64; off <<= 1) {
      int t = __shfl_up(sc, off);
      if (lane >= off) sc += t;
    }
    if (lane == 63) wsum[wid] = sc;
    int carry0 = carry_s;
    __syncthreads();
    if (wid == 0) {
      int w = (lane < 16) ? wsum[lane] : 0;
      int swc = w;
      #pragma unroll
      for (int off = 1; off < 16; off <<= 1) {
        int t = __shfl_up(swc, off);
        if (lane >= off) swc += t;
      }
      if (lane < 16) wsum[lane] = swc - w;
      if (lane == 15) carry_s = carry0 + swc;
    }
    __syncthreads();
    if (i < n) row_ptr[i] = carry0 + wsum[wid] + sc - v;
    __syncthreads();
  }
  if (threadIdx.x == 0) row_ptr[n] = carry_s;
}

__global__ void k_scatter(const int* __restrict__ ei, const int* __restrict__ row_ptr,
                          int* __restrict__ cursor, int* __restrict__ csr_src,
                          int* __restrict__ csr_eid, int* __restrict__ csr_pos, int nE) {
  int e = blockIdx.x * 256 + threadIdx.x;
  if (e >= nE) return;
  int dst = ei[nE + e];
  int pos = row_ptr[dst] + atomicAdd(&cursor[dst], 1);
  csr_src[pos] = ei[e];
  csr_eid[pos] = e;
  csr_pos[e] = pos;
}

// ---------- stream-read edge_attr, scatter-write bf16 rows into CSR order ----------
__global__ __launch_bounds__(256) void k_eascatter(const float* __restrict__ ea,
                                                   const int* __restrict__ csr_pos,
                                                   ushort* __restrict__ eaP, int nE) {
  int lane = threadIdx.x & 63, grp = lane >> 5, l5 = lane & 31;
  int wv = (blockIdx.x * 256 + threadIdx.x) >> 6;
  int nW = gridDim.x * 4;
  for (int base = wv * 16; base < nE; base += nW * 16) {
    int idx = base + (lane & 15);
    int posv = csr_pos[idx < nE ? idx : nE - 1];
    #pragma unroll
    for (int j = 0; j < 8; ++j) {
      int e = base + 2 * j + grp;
      int pos = __shfl(posv, 2 * j + grp);
      if (e < nE) {
        float2 v = *(const float2*)&ea[(size_t)e * DE + l5 * 2];
        ushort2 o; o.x = f2bf(v.x); o.y = f2bf(v.y);
        *(ushort2*)&eaP[(size_t)pos * DE + l5 * 2] = o;
      }
    }
  }
}

// ---------- GEMM1 (MFMA bf16): xwsb[n][256] = bf16( (x @ W1) * dinv[n] ) ----------
__global__ __launch_bounds__(256) void k_gemm1(const float* __restrict__ x,
                                               const ushort* __restrict__ Wp1,
                                               const float* __restrict__ dinv,
                                               ushort* __restrict__ xwsb, int nN) {
  int lane = threadIdx.x & 63, wave = threadIdx.x >> 6;
  int l15 = lane & 15, lh = lane >> 4;
  int m0 = blockIdx.x * 16;
  int rowa = m0 + l15; if (rowa >= nN) rowa = nN - 1;
  f32x4 acc[4] = {};
  for (int s = 0; s < 4; ++s) {
    const float* ap = &x[(size_t)rowa * DN + s * 32 + lh * 8];
    float4 a0 = *(const float4*)ap;
    float4 a1 = *(const float4*)(ap + 4);
    bf16x8 af;
    af[0] = (short)f2bf(a0.x); af[1] = (short)f2bf(a0.y);
    af[2] = (short)f2bf(a0.z); af[3] = (short)f2bf(a0.w);
    af[4] = (short)f2bf(a1.x); af[5] = (short)f2bf(a1.y);
    af[6] = (short)f2bf(a1.z); af[7] = (short)f2bf(a1.w);
    #pragma unroll
    for (int tt = 0; tt < 4; ++tt) {
      int t = wave * 4 + tt;
      bf16x8 bf = *(const bf16x8*)&Wp1[((t * 4 + s) * 64 + lane) * 8];
      acc[tt] = __builtin_amdgcn_mfma_f32_16x16x32_bf16(af, bf, acc[tt], 0, 0, 0);
    }
  }
  #pragma unroll
  for (int tt = 0; tt < 4; ++tt) {
    int c = (wave * 4 + tt) * 16 + l15;
    #pragma unroll
    for (int r = 0; r < 4; ++r) {
      int row = m0 + lh * 4 + r;
      if (row < nN) xwsb[(size_t)row * DHID + c] = f2bf(acc[tt][r] * dinv[row]);
    }
  }
}

// ---------- GEMM2 (MFMA bf16): qrb (bf16 q|hr|wqe) + kvb (bf16 interleaved) ----------
__global__ __launch_bounds__(256) void k_gemm2(const ushort* __restrict__ hb,
                                               const ushort* __restrict__ Wp2,
                                               const float* __restrict__ bcat,
                                               ushort* __restrict__ qrb,
                                               ushort* __restrict__ kvb, int nN) {
  int lane = threadIdx.x & 63, wave = threadIdx.x >> 6;
  int l15 = lane & 15, lh = lane >> 4;
  int m0 = blockIdx.x * 16;
  int rowa = m0 + l15; if (rowa >= nN) rowa = nN - 1;
  f32x4 acc[9] = {};
  for (int s = 0; s < 8; ++s) {
    bf16x8 af = *(const bf16x8*)&hb[(size_t)rowa * DHID + s * 32 + lh * 8];
    #pragma unroll
    for (int tt = 0; tt < 9; ++tt) {
      int t = wave * 9 + tt;
      bf16x8 bf = *(const bf16x8*)&Wp2[((t * 8 + s) * 64 + lane) * 8];
      acc[tt] = __builtin_amdgcn_mfma_f32_16x16x32_bf16(af, bf, acc[tt], 0, 0, 0);
    }
  }
  #pragma unroll
  for (int tt = 0; tt < 9; ++tt) {
    int c = (wave * 9 + tt) * 16 + l15;
    float bc = bcat[c];
    #pragma unroll
    for (int r = 0; r < 4; ++r) {
      int row = m0 + lh * 4 + r;
      if (row >= nN) continue;
      float val = acc[tt][r] + bc;
      if (c < 128)      qrb[(size_t)row * 320 + c] = f2bf(val);
      else if (c < 384) kvb[(size_t)row * 256 + (c - 128)] = f2bf(val);
      else if (c < 512) qrb[(size_t)row * 320 + 128 + (c - 384)] = f2bf(val);
      else              qrb[(size_t)row * 320 + 256 + (c - 512)] = f2bf(val);
    }
  }
}

// ---------- GCN aggregate: 2 waves per node, LDS combine, no global atomics ----------
__global__ __launch_bounds__(256) void k_gcn2w(const ushort* __restrict__ xwsb,
                                               const int* __restrict__ row_ptr,
                                               const int* __restrict__ csr_src,
                                               const float* __restrict__ dinv,
                                               const float* __restrict__ b1,
                                               ushort* __restrict__ hb, int nN) {
  __shared__ float lds[2][2][256];
  int lane = threadIdx.x & 63, wid = threadIdx.x >> 6;
  int slot = wid >> 1, half = wid & 1;
  int grp = lane >> 5, l5 = lane & 31;
  int n = blockIdx.x * 2 + slot;
  bool valid = (n < nN);
  float acc[8] = {};
  if (valid) {
    int beg = row_ptr[n], end = row_ptr[n + 1];
    for (int i0 = beg + 16 * half; i0 < end; i0 += 32) {
      int cnt = end - i0; if (cnt > 16) cnt = 16;
      int li = lane & 15; if (li >= cnt) li = cnt - 1;
      int srcv = csr_src[i0 + li];
      uint4 xv[8];
      #pragma unroll
      for (int j = 0; j < 8; ++j) {
        int sj = __shfl(srcv, 2 * j + grp);
        xv[j] = *(const uint4*)&xwsb[(size_t)sj * DHID + l5 * 8];
      }
      #pragma unroll
      for (int j = 0; j < 8; ++j) {
        float w = (2 * j + grp < cnt) ? 1.f : 0.f;
        unsigned q[4] = {xv[j].x, xv[j].y, xv[j].z, xv[j].w};
        #pragma unroll
        for (int d = 0; d < 4; ++d) {
          acc[2*d]   = fmaf(w, __uint_as_float(q[d] << 16), acc[2*d]);
          acc[2*d+1] = fmaf(w, __uint_as_float(q[d] & 0xFFFF0000u), acc[2*d+1]);
        }
      }
    }
  }
  #pragma unroll
  for (int d = 0; d < 8; ++d) acc[d] += __shfl_xor(acc[d], 32);
  if (valid && grp == 0) {
    #pragma unroll
    for (int d = 0; d < 8; ++d) lds[slot][half][l5 * 8 + d] = acc[d];
  }
  __syncthreads();
  if (valid && half == 0) {
    int d0 = lane * 4;
    float g0 = lds[slot][0][d0 + 0] + lds[slot][1][d0 + 0];
    float g1 = lds[slot][0][d0 + 1] + lds[slot][1][d0 + 1];
    float g2 = lds[slot][0][d0 + 2] + lds[slot][1][d0 + 2];
    float g3 = lds[slot][0][d0 + 3] + lds[slot][1][d0 + 3];
    ushort4 sv = *(const ushort4*)&xwsb[(size_t)n * DHID + d0];
    float4 bb = *(const float4*)&b1[d0];
    float dn = dinv[n];
    ushort4 o;
    o.x = f2bf(fmaxf((g0 + bf2f(sv.x)) * dn + bb.x, 0.f));
    o.y = f2bf(fmaxf((g1 + bf2f(sv.y)) * dn + bb.y, 0.f));
    o.z = f2bf(fmaxf((g2 + bf2f(sv.z)) * dn + bb.z, 0.f));
    o.w = f2bf(fmaxf((g3 + bf2f(sv.w)) * dn + bb.w, 0.f));
    *(ushort4*)&hb[(size_t)n * DHID + d0] = o;
  }
}

// ---------- attention: 2 waves per node, LDS combine, fused epilogue ----------
template<int EAP>
__global__ __launch_bounds__(256) void k_attn2w(const ushort* __restrict__ qrb,
                                                const ushort* __restrict__ kvb,
                                                const ushort* __restrict__ eaP,
                                                const float* __restrict__ ea32,
                                                const int* __restrict__ csr_src,
                                                const int* __restrict__ csr_eid,
                                                const int* __restrict__ row_ptr,
                                                const int* __restrict__ batch,
                                                const float* __restrict__ We,
                                                const float* __restrict__ gamma,
                                                const float* __restrict__ beta,
                                                float* __restrict__ pool,
                                                float* __restrict__ cnt, int nN) {
  __shared__ float l_s[2][2];
  __shared__ float l_v[2][2][128];
  __shared__ float l_e[2][2][64];
  int lane = threadIdx.x & 63, wid = threadIdx.x >> 6;
  int slot = wid >> 1, half = wid & 1;
  int grp = lane >> 5, l5 = lane & 31;
  int n = blockIdx.x * 2 + slot;
  bool valid = (n < nN);
  float ps = 0.f;
  float4 pv = {0, 0, 0, 0};
  float2 pe = {0, 0};
  if (valid) {
    const ushort* qb = &qrb[(size_t)n * 320];
    ushort4 qv = *(const ushort4*)&qb[l5 * 4];
    ushort2 wv = *(const ushort2*)&qb[256 + l5 * 2];
    float q0 = bf2f(qv.x), q1 = bf2f(qv.y), q2 = bf2f(qv.z), q3 = bf2f(qv.w);
    float we0 = bf2f(wv.x), we1 = bf2f(wv.y);
    int beg = row_ptr[n], end = row_ptr[n + 1];
    for (int i0 = beg + 16 * half; i0 < end; i0 += 32) {
      int cnt = end - i0; if (cnt > 16) cnt = 16;
      int li = lane & 15; if (li >= cnt) li = cnt - 1;
      int srcv = csr_src[i0 + li];
      int eidv = 0;
      if (!EAP) eidv = csr_eid[i0 + li];
      uint4 kv[8]; float2 eav[8];
      #pragma unroll
      for (int j = 0; j < 8; ++j) {
        int sj = __shfl(srcv, 2 * j + grp);
        kv[j] = *(const uint4*)&kvb[(size_t)sj * DHID + l5 * 8];
        if (EAP) {
          int pj = 2 * j + grp; if (pj >= cnt) pj = cnt - 1;
          ushort2 e2 = *(const ushort2*)&eaP[(size_t)(i0 + pj) * DE + l5 * 2];
          eav[j].x = bf2f(e2.x); eav[j].y = bf2f(e2.y);
        } else {
          int ej = __shfl(eidv, 2 * j + grp);
          eav[j] = *(const float2*)&ea32[(size_t)ej * DE + l5 * 2];
        }
      }
      #pragma unroll
      for (int j = 0; j < 8; ++j) {
        float k0 = __uint_as_float(kv[j].x << 16);
        float k1 = __uint_as_float(kv[j].x & 0xFFFF0000u);
        float k2 = __uint_as_float(kv[j].y << 16);
        float k3 = __uint_as_float(kv[j].y & 0xFFFF0000u);
        float part = q0*k0 + q1*k1 + q2*k2 + q3*k3 + we0*eav[j].x + we1*eav[j].y;
        #pragma unroll
        for (int off = 1; off < 32; off <<= 1) part += __shfl_xor(part, off);
        float p = (2 * j + grp < cnt) ? __expf(part) : 0.f;
        ps += p;
        pv.x += p * __uint_as_float(kv[j].z << 16);
        pv.y += p * __uint_as_float(kv[j].z & 0xFFFF0000u);
        pv.z += p * __uint_as_float(kv[j].w << 16);
        pv.w += p * __uint_as_float(kv[j].w & 0xFFFF0000u);
        pe.x += p * eav[j].x;
        pe.y += p * eav[j].y;
      }
    }
  }
  ps   += __shfl_xor(ps, 32);
  pv.x += __shfl_xor(pv.x, 32); pv.y += __shfl_xor(pv.y, 32);
  pv.z += __shfl_xor(pv.z, 32); pv.w += __shfl_xor(pv.w, 32);
  pe.x += __shfl_xor(pe.x, 32); pe.y += __shfl_xor(pe.y, 32);
  if (valid && grp == 0) {
    if (l5 == 0) l_s[slot][half] = ps;
    l_v[slot][half][l5 * 4 + 0] = pv.x;
    l_v[slot][half][l5 * 4 + 1] = pv.y;
    l_v[slot][half][l5 * 4 + 2] = pv.z;
    l_v[slot][half][l5 * 4 + 3] = pv.w;
    l_e[slot][half][l5 * 2 + 0] = pe.x;
    l_e[slot][half][l5 * 2 + 1] = pe.y;
  }
  __syncthreads();
  if (valid && half == 0) {
    float s = l_s[slot][0] + l_s[slot][1];
    float inv = (s > 0.f) ? 1.f / s : 0.f;
    float4 o4;
    o4.x = (l_v[slot][0][l5*4+0] + l_v[slot][1][l5*4+0]) * inv;
    o4.y = (l_v[slot][0][l5*4+1] + l_v[slot][1][l5*4+1]) * inv;
    o4.z = (l_v[slot][0][l5*4+2] + l_v[slot][1][l5*4+2]) * inv;
    o4.w = (l_v[slot][0][l5*4+3] + l_v[slot][1][l5*4+3]) * inv;
    float ex = (l_e[slot][0][l5*2+0] + l_e[slot][1][l5*2+0]) * inv;
    float ey = (l_e[slot][0][l5*2+1] + l_e[slot][1][l5*2+1]) * inv;
    int gb = grp << 5;
    #pragma unroll 8
    for (int c = 0; c < 64; c += 2) {
      float e0 = __shfl(ex, (c >> 1) + gb);
      float e1 = __shfl(ey, (c >> 1) + gb);
      float4 w0 = *(const float4*)&We[c * DEMB + l5 * 4];
      float4 w1 = *(const float4*)&We[(c + 1) * DEMB + l5 * 4];
      o4.x += e0 * w0.x + e1 * w1.x;
      o4.y += e0 * w0.y + e1 * w1.y;
      o4.z += e0 * w0.z + e1 * w1.z;
      o4.w += e0 * w0.w + e1 * w1.w;
    }
    ushort4 hv = *(const ushort4*)&qrb[(size_t)n * 320 + 128 + l5 * 4];
    o4.x += bf2f(hv.x); o4.y += bf2f(hv.y); o4.z += bf2f(hv.z); o4.w += bf2f(hv.w);
    float s1 = o4.x + o4.y + o4.z + o4.w;
    float sq = o4.x*o4.x + o4.y*o4.y + o4.z*o4.z + o4.w*o4.w;
    #pragma unroll
    for (int off = 1; off < 32; off <<= 1) {
      s1 += __shfl_xor(s1, off);
      sq += __shfl_xor(sq, off);
    }
    float mu = s1 * (1.f / 128.f);
    float var = sq * (1.f / 128.f) - mu * mu;
    float rstd = rsqrtf(var + 1e-5f);
    float4 g4 = *(const float4*)&gamma[l5 * 4];
    float4 b4 = *(const float4*)&beta[l5 * 4];
    if (grp == 0) {
      int b = batch[n];
      atomicAdd(&pool[b * DEMB + l5 * 4 + 0], fmaxf((o4.x - mu) * rstd * g4.x + b4.x, 0.f));
      atomicAdd(&pool[b * DEMB + l5 * 4 + 1], fmaxf((o4.y - mu) * rstd * g4.y + b4.y, 0.f));
      atomicAdd(&pool[b * DEMB + l5 * 4 + 2], fmaxf((o4.z - mu) * rstd * g4.z + b4.z, 0.f));
      atomicAdd(&pool[b * DEMB + l5 * 4 + 3], fmaxf((o4.w - mu) * rstd * g4.w + b4.w, 0.f));
      if (l5 == 0) atomicAdd(&cnt[b], 1.f);
    }
  }
}

__global__ void k_final(const float* __restrict__ pool, const float* __restrict__ cnt,
                        float* __restrict__ out, int total) {
  int i = blockIdx.x * 256 + threadIdx.x;
  if (i < total) out[i] = pool[i] / fmaxf(cnt[i >> 7], 1.f);
}

extern "C" void kernel_launch(void* const* d_in, const int* in_sizes, int n_in,
                              void* d_out, int out_size, void* d_ws, size_t ws_size,
                              hipStream_t stream) {
  const float* x         = (const float*)d_in[0];
  const float* edge_attr = (const float*)d_in[1];
  const int*   edge_index= (const int*)d_in[2];
  const int*   batch     = (const int*)d_in[3];
  const float* W1 = (const float*)d_in[4];
  const float* b1 = (const float*)d_in[5];
  const float* Wq = (const float*)d_in[6];  const float* bq = (const float*)d_in[7];
  const float* Wk = (const float*)d_in[8];  const float* bk = (const float*)d_in[9];
  const float* Wv = (const float*)d_in[10]; const float* bv = (const float*)d_in[11];
  const float* We = (const float*)d_in[12]; const float* be = (const float*)d_in[13];
  const float* Wr = (const float*)d_in[14]; const float* br = (const float*)d_in[15];
  const float* gamma = (const float*)d_in[16];
  const float* beta  = (const float*)d_in[17];
  float* out = (float*)d_out;

  const int nN = in_sizes[0] / DN;       // 50000
  const int nE = in_sizes[1] / DE;       // 1600000

  char* p = (char*)d_ws;
  auto alloc = [&](size_t bytes) -> void* {
    void* r = (void*)p;
    p += (bytes + 255) & ~(size_t)255;
    return r;
  };
  // ---- zeroed region (small) ----
  int*   degi   = (int*)  alloc((size_t)nN * 4);
  int*   cursor = (int*)  alloc((size_t)nN * 4);
  float* pool   = (float*)alloc((size_t)out_size * 4);
  float* cnt    = (float*)alloc(64 * 4);
  size_t zero_bytes = (size_t)(p - (char*)d_ws);
  // ---- non-zeroed ----
  int*    row_ptr = (int*)   alloc((size_t)(nN + 1) * 4);
  float*  dinv    = (float*) alloc((size_t)nN * 4);
  int*    csr_src = (int*)   alloc((size_t)nE * 4);
  int*    csr_eid = (int*)   alloc((size_t)nE * 4);
  int*    csr_pos = (int*)   alloc((size_t)nE * 4);
  ushort* Wp1     = (ushort*)alloc((size_t)16 * 4 * 64 * 8 * 2);
  ushort* Wp2     = (ushort*)alloc((size_t)36 * 8 * 64 * 8 * 2);
  float*  bcat    = (float*) alloc(576 * 4);
  ushort* hb      = (ushort*)alloc((size_t)nN * DHID * 2);
  ushort* qrb     = (ushort*)alloc((size_t)nN * 320 * 2);
  ushort* xwsb    = (ushort*)alloc((size_t)nN * DHID * 2);  // aliased: xws then kv
  ushort* kvb     = xwsb;   // xws dead after k_gcn2w; gemm2 overwrites as kv table
  size_t base_required = (size_t)(p - (char*)d_ws);
  if (ws_size < base_required) return;
  // optional: edge_attr in CSR order, bf16 (enables streamed reads in attn)
  ushort* eaP = nullptr;
  size_t eap_bytes = (((size_t)nE * DE * 2) + 255) & ~(size_t)255;
  if (ws_size >= base_required + eap_bytes) eaP = (ushort*)alloc(eap_bytes);

  hipMemsetAsync(d_ws, 0, zero_bytes, stream);

  k_prep1<<<128, 256, 0, stream>>>(W1, Wp1);
  k_prep2<<<576, 256, 0, stream>>>(Wq, Wk, Wv, Wr, We, Wp2);
  k_prep_b<<<3, 256, 0, stream>>>(bq, bk, bv, br, be, We, bcat);
  k_deg<<<(nE + 255) / 256, 256, 0, stream>>>(edge_index, degi, nE);
  k_dinv<<<(nN + 255) / 256, 256, 0, stream>>>(degi, dinv, nN);
  k_scan<<<1, 1024, 0, stream>>>(degi, row_ptr, nN);
  k_scatter<<<(nE + 255) / 256, 256, 0, stream>>>(edge_index, row_ptr, cursor,
                                                  csr_src, csr_eid, csr_pos, nE);
  if (eaP)
    k_eascatter<<<2048, 256, 0, stream>>>(edge_attr, csr_pos, eaP, nE);
  k_gemm1<<<(nN + 15) / 16, 256, 0, stream>>>(x, Wp1, dinv, xwsb, nN);
  k_gcn2w<<<(nN + 1) / 2, 256, 0, stream>>>(xwsb, row_ptr, csr_src, dinv, b1, hb, nN);
  k_gemm2<<<(nN + 15) / 16, 256, 0, stream>>>(hb, Wp2, bcat, qrb, kvb, nN);
  if (eaP)
    k_attn2w<1><<<(nN + 1) / 2, 256, 0, stream>>>(qrb, kvb, eaP, edge_attr, csr_src,
                                                  csr_eid, row_ptr, batch, We, gamma,
                                                  beta, pool, cnt, nN);
  else
    k_attn2w<0><<<(nN + 1) / 2, 256, 0, stream>>>(qrb, kvb, eaP, edge_attr, csr_src,
                                                  csr_eid, row_ptr, batch, We, gamma,
                                                  beta, pool, cnt, nN);
  k_final<<<(out_size + 255) / 256, 256, 0, stream>>>(pool, cnt, out, out_size);
}

// Round 8
// 1184.804 us; speedup vs baseline: 1.8980x; 1.0916x over previous
//
#include <hip/hip_runtime.h>

typedef short bf16x8 __attribute__((ext_vector_type(8)));
typedef float f32x4 __attribute__((ext_vector_type(4)));

#define DN 128
#define DE 64
#define DEMB 128
#define DHID 256
#define SCALE 0.08838834764831845f  // 1/sqrt(128)
#define PCHUNK 2048

__device__ __forceinline__ ushort f2bf(float f) {
  unsigned u = __float_as_uint(f);
  return (ushort)((u + 0x7FFFu + ((u >> 16) & 1u)) >> 16);  // RNE
}
__device__ __forceinline__ float bf2f(ushort u) {
  return __uint_as_float((unsigned)u << 16);
}

// ---------- weight pack for GEMM1: W1[128][256] -> frag order, bf16 ----------
__global__ void k_prep1(const float* __restrict__ W1, ushort* __restrict__ Wp1) {
  int idx = blockIdx.x * 256 + threadIdx.x;
  if (idx >= 16 * 4 * 64 * 8) return;
  int j = idx & 7, lane = (idx >> 3) & 63, s = (idx >> 9) & 3, t = idx >> 11;
  int k = s * 32 + (lane >> 4) * 8 + j;
  int c = t * 16 + (lane & 15);
  Wp1[idx] = f2bf(W1[k * DHID + c]);
}

// ---------- weight pack for GEMM2: Wcat[256][576] = [Wq*s | Wk | Wv | Wr | (Wq@We^T)*s] ----------
__global__ void k_prep2(const float* __restrict__ Wq, const float* __restrict__ Wk,
                        const float* __restrict__ Wv, const float* __restrict__ Wr,
                        const float* __restrict__ We, ushort* __restrict__ Wp2) {
  int idx = blockIdx.x * 256 + threadIdx.x;
  if (idx >= 36 * 8 * 64 * 8) return;
  int j = idx & 7, lane = (idx >> 3) & 63, s = (idx >> 9) & 7, t = idx >> 12;
  int k = s * 32 + (lane >> 4) * 8 + j;
  int c = t * 16 + (lane & 15);
  float v;
  if (c < 128)       v = Wq[k * DEMB + c] * SCALE;
  else if (c < 256)  v = Wk[k * DEMB + (c - 128)];
  else if (c < 384)  v = Wv[k * DEMB + (c - 256)];
  else if (c < 512)  v = Wr[k * DEMB + (c - 384)];
  else {
    int cc = c - 512;
    float a = 0.f;
    for (int u = 0; u < DEMB; ++u) a += Wq[k * DEMB + u] * We[cc * DEMB + u];
    v = a * SCALE;
  }
  Wp2[idx] = f2bf(v);
}

__global__ void k_prep_b(const float* __restrict__ bq, const float* __restrict__ bk,
                         const float* __restrict__ bv, const float* __restrict__ br,
                         const float* __restrict__ be, const float* __restrict__ We,
                         float* __restrict__ bcat) {
  int j = blockIdx.x * 256 + threadIdx.x;
  if (j >= 576) return;
  float v;
  if (j < 128)       v = bq[j] * SCALE;
  else if (j < 256)  v = bk[j - 128] + be[j - 128];
  else if (j < 384)  v = bv[j - 256] + be[j - 256];
  else if (j < 512)  v = br[j - 384];
  else {
    int cc = j - 512;
    float a = 0.f;
    for (int u = 0; u < DEMB; ++u) a += bq[u] * We[cc * DEMB + u];
    v = a * SCALE;
  }
  bcat[j] = v;
}

// ---------- CSR build ----------
__global__ void k_deg(const int* __restrict__ ei, int* __restrict__ degi, int nE) {
  int e = blockIdx.x * 256 + threadIdx.x;
  if (e < nE) atomicAdd(&degi[ei[nE + e]], 1);
}

__global__ void k_dinv(const int* __restrict__ degi, float* __restrict__ dinv, int nN) {
  int n = blockIdx.x * 256 + threadIdx.x;
  if (n < nN) dinv[n] = rsqrtf(1.0f + (float)degi[n]);
}

__global__ __launch_bounds__(1024) void k_scan(const int* __restrict__ degi,
                                               int* __restrict__ row_ptr, int n) {
  __shared__ int wsum[16];
  __shared__ int carry_s;
  int lane = threadIdx.x & 63, wid = threadIdx.x >> 6;
  if (threadIdx.x == 0) carry_s = 0;
  __syncthreads();
  for (int base = 0; base < n; base += 1024) {
    int i = base + threadIdx.x;
    int v = (i < n) ? degi[i] : 0;
    int sc = v;
    #pragma unroll
    for (int off = 1; off < 64; off <<= 1) {
      int t = __shfl_up(sc, off);
      if (lane >= off) sc += t;
    }
    if (lane == 63) wsum[wid] = sc;
    int carry0 = carry_s;
    __syncthreads();
    if (wid == 0) {
      int w = (lane < 16) ? wsum[lane] : 0;
      int swc = w;
      #pragma unroll
      for (int off = 1; off < 16; off <<= 1) {
        int t = __shfl_up(swc, off);
        if (lane >= off) swc += t;
      }
      if (lane < 16) wsum[lane] = swc - w;
      if (lane == 15) carry_s = carry0 + swc;
    }
    __syncthreads();
    if (i < n) row_ptr[i] = carry0 + wsum[wid] + sc - v;
    __syncthreads();
  }
  if (threadIdx.x == 0) row_ptr[n] = carry_s;
}

// csr_sd[pos] = src | ((dst&15)<<16); also csr_eid (fallback) and csr_pos (for eascatter)
__global__ void k_scatter(const int* __restrict__ ei, const int* __restrict__ row_ptr,
                          int* __restrict__ cursor, int* __restrict__ csr_sd,
                          int* __restrict__ csr_eid, int* __restrict__ csr_pos, int nE) {
  int e = blockIdx.x * 256 + threadIdx.x;
  if (e >= nE) return;
  int dst = ei[nE + e];
  int pos = row_ptr[dst] + atomicAdd(&cursor[dst], 1);
  csr_sd[pos] = (ei[e] & 0xFFFF) | ((dst & 15) << 16);
  csr_eid[pos] = e;
  csr_pos[e] = pos;
}

// ---------- stream-read edge_attr, scatter-write bf16 rows into CSR order ----------
__global__ __launch_bounds__(256) void k_eascatter(const float* __restrict__ ea,
                                                   const int* __restrict__ csr_pos,
                                                   ushort* __restrict__ eaP, int nE) {
  int lane = threadIdx.x & 63, grp = lane >> 5, l5 = lane & 31;
  int wv = (blockIdx.x * 256 + threadIdx.x) >> 6;
  int nW = gridDim.x * 4;
  for (int base = wv * 16; base < nE; base += nW * 16) {
    int idx = base + (lane & 15);
    int posv = csr_pos[idx < nE ? idx : nE - 1];
    #pragma unroll
    for (int j = 0; j < 8; ++j) {
      int e = base + 2 * j + grp;
      int pos = __shfl(posv, 2 * j + grp);
      if (e < nE) {
        float2 v = *(const float2*)&ea[(size_t)e * DE + l5 * 2];
        ushort2 o; o.x = f2bf(v.x); o.y = f2bf(v.y);
        *(ushort2*)&eaP[(size_t)pos * DE + l5 * 2] = o;
      }
    }
  }
}

// ---------- GEMM1 (MFMA bf16): xwsb[n][256] = bf16( (x @ W1) * dinv[n] ) ----------
__global__ __launch_bounds__(256) void k_gemm1(const float* __restrict__ x,
                                               const ushort* __restrict__ Wp1,
                                               const float* __restrict__ dinv,
                                               ushort* __restrict__ xwsb, int nN) {
  int lane = threadIdx.x & 63, wave = threadIdx.x >> 6;
  int l15 = lane & 15, lh = lane >> 4;
  int m0 = blockIdx.x * 16;
  int rowa = m0 + l15; if (rowa >= nN) rowa = nN - 1;
  f32x4 acc[4] = {};
  for (int s = 0; s < 4; ++s) {
    const float* ap = &x[(size_t)rowa * DN + s * 32 + lh * 8];
    float4 a0 = *(const float4*)ap;
    float4 a1 = *(const float4*)(ap + 4);
    bf16x8 af;
    af[0] = (short)f2bf(a0.x); af[1] = (short)f2bf(a0.y);
    af[2] = (short)f2bf(a0.z); af[3] = (short)f2bf(a0.w);
    af[4] = (short)f2bf(a1.x); af[5] = (short)f2bf(a1.y);
    af[6] = (short)f2bf(a1.z); af[7] = (short)f2bf(a1.w);
    #pragma unroll
    for (int tt = 0; tt < 4; ++tt) {
      int t = wave * 4 + tt;
      bf16x8 bf = *(const bf16x8*)&Wp1[((t * 4 + s) * 64 + lane) * 8];
      acc[tt] = __builtin_amdgcn_mfma_f32_16x16x32_bf16(af, bf, acc[tt], 0, 0, 0);
    }
  }
  #pragma unroll
  for (int tt = 0; tt < 4; ++tt) {
    int c = (wave * 4 + tt) * 16 + l15;
    #pragma unroll
    for (int r = 0; r < 4; ++r) {
      int row = m0 + lh * 4 + r;
      if (row < nN) xwsb[(size_t)row * DHID + c] = f2bf(acc[tt][r] * dinv[row]);
    }
  }
}

// ---------- GEMM2 (MFMA bf16): emits qtb[192], kb[128], vb[128], hrb[128] (all bf16) ----------
__global__ __launch_bounds__(256) void k_gemm2(const ushort* __restrict__ hb,
                                               const ushort* __restrict__ Wp2,
                                               const float* __restrict__ bcat,
                                               ushort* __restrict__ qtb,
                                               ushort* __restrict__ kb,
                                               ushort* __restrict__ vb,
                                               ushort* __restrict__ hrb, int nN) {
  int lane = threadIdx.x & 63, wave = threadIdx.x >> 6;
  int l15 = lane & 15, lh = lane >> 4;
  int m0 = blockIdx.x * 16;
  int rowa = m0 + l15; if (rowa >= nN) rowa = nN - 1;
  f32x4 acc[9] = {};
  for (int s = 0; s < 8; ++s) {
    bf16x8 af = *(const bf16x8*)&hb[(size_t)rowa * DHID + s * 32 + lh * 8];
    #pragma unroll
    for (int tt = 0; tt < 9; ++tt) {
      int t = wave * 9 + tt;
      bf16x8 bf = *(const bf16x8*)&Wp2[((t * 8 + s) * 64 + lane) * 8];
      acc[tt] = __builtin_amdgcn_mfma_f32_16x16x32_bf16(af, bf, acc[tt], 0, 0, 0);
    }
  }
  #pragma unroll
  for (int tt = 0; tt < 9; ++tt) {
    int c = (wave * 9 + tt) * 16 + l15;
    float bc = bcat[c];
    #pragma unroll
    for (int r = 0; r < 4; ++r) {
      int row = m0 + lh * 4 + r;
      if (row >= nN) continue;
      ushort val = f2bf(acc[tt][r] + bc);
      if (c < 128)      qtb[(size_t)row * 192 + c] = val;
      else if (c < 256) kb[(size_t)row * 128 + (c - 128)] = val;
      else if (c < 384) vb[(size_t)row * 128 + (c - 256)] = val;
      else if (c < 512) hrb[(size_t)row * 128 + (c - 384)] = val;
      else              qtb[(size_t)row * 192 + 128 + (c - 512)] = val;
    }
  }
}

// ---------- GCN aggregate: 2 waves per node, LDS combine ----------
__global__ __launch_bounds__(256) void k_gcn2w(const ushort* __restrict__ xwsb,
                                               const int* __restrict__ row_ptr,
                                               const int* __restrict__ csr_sd,
                                               const float* __restrict__ dinv,
                                               const float* __restrict__ b1,
                                               ushort* __restrict__ hb, int nN) {
  __shared__ float lds[2][2][256];
  int lane = threadIdx.x & 63, wid = threadIdx.x >> 6;
  int slot = wid >> 1, half = wid & 1;
  int grp = lane >> 5, l5 = lane & 31;
  int n = blockIdx.x * 2 + slot;
  bool valid = (n < nN);
  float acc[8] = {};
  if (valid) {
    int beg = row_ptr[n], end = row_ptr[n + 1];
    for (int i0 = beg + 16 * half; i0 < end; i0 += 32) {
      int cnt = end - i0; if (cnt > 16) cnt = 16;
      int li = lane & 15; if (li >= cnt) li = cnt - 1;
      int srcv = csr_sd[i0 + li] & 0xFFFF;
      uint4 xv[8];
      #pragma unroll
      for (int j = 0; j < 8; ++j) {
        int sj = __shfl(srcv, 2 * j + grp);
        xv[j] = *(const uint4*)&xwsb[(size_t)sj * DHID + l5 * 8];
      }
      #pragma unroll
      for (int j = 0; j < 8; ++j) {
        float w = (2 * j + grp < cnt) ? 1.f : 0.f;
        unsigned q[4] = {xv[j].x, xv[j].y, xv[j].z, xv[j].w};
        #pragma unroll
        for (int d = 0; d < 4; ++d) {
          acc[2*d]   = fmaf(w, __uint_as_float(q[d] << 16), acc[2*d]);
          acc[2*d+1] = fmaf(w, __uint_as_float(q[d] & 0xFFFF0000u), acc[2*d+1]);
        }
      }
    }
  }
  #pragma unroll
  for (int d = 0; d < 8; ++d) acc[d] += __shfl_xor(acc[d], 32);
  if (valid && grp == 0) {
    #pragma unroll
    for (int d = 0; d < 8; ++d) lds[slot][half][l5 * 8 + d] = acc[d];
  }
  __syncthreads();
  if (valid && half == 0) {
    int d0 = lane * 4;
    float g0 = lds[slot][0][d0 + 0] + lds[slot][1][d0 + 0];
    float g1 = lds[slot][0][d0 + 1] + lds[slot][1][d0 + 1];
    float g2 = lds[slot][0][d0 + 2] + lds[slot][1][d0 + 2];
    float g3 = lds[slot][0][d0 + 3] + lds[slot][1][d0 + 3];
    ushort4 sv = *(const ushort4*)&xwsb[(size_t)n * DHID + d0];
    float4 bb = *(const float4*)&b1[d0];
    float dn = dinv[n];
    ushort4 o;
    o.x = f2bf(fmaxf((g0 + bf2f(sv.x)) * dn + bb.x, 0.f));
    o.y = f2bf(fmaxf((g1 + bf2f(sv.y)) * dn + bb.y, 0.f));
    o.z = f2bf(fmaxf((g2 + bf2f(sv.z)) * dn + bb.z, 0.f));
    o.w = f2bf(fmaxf((g3 + bf2f(sv.w)) * dn + bb.w, 0.f));
    *(ushort4*)&hb[(size_t)n * DHID + d0] = o;
  }
}

// ---------- attention per 16-node tile: MFMA logits (phase1) + gather-FMA PV (phase2) ----------
template<int EAP>
__global__ __launch_bounds__(256) void k_attnT(const ushort* __restrict__ qtb,
                                               const ushort* __restrict__ kb,
                                               const ushort* __restrict__ vb,
                                               const ushort* __restrict__ hrb,
                                               const ushort* __restrict__ eaP,
                                               const float* __restrict__ ea32,
                                               const int* __restrict__ csr_sd,
                                               const int* __restrict__ csr_eid,
                                               const int* __restrict__ row_ptr,
                                               const int* __restrict__ batch,
                                               const float* __restrict__ We,
                                               const float* __restrict__ gamma,
                                               const float* __restrict__ beta,
                                               float* __restrict__ pool,
                                               float* __restrict__ cnt, int nN) {
  __shared__ float pbuf[PCHUNK];
  int lane = threadIdx.x & 63, wid = threadIdx.x >> 6;
  int l15 = lane & 15, lh = lane >> 4, grp = lane >> 5, l5 = lane & 31;
  int n0 = blockIdx.x * 16;
  int nTop = n0 + 16 < nN ? n0 + 16 : nN;
  int tbeg = row_ptr[n0], tend = row_ptr[nTop];
  // Q-tile A-fragments (16 rows x 192 dims, verified k_gemm1 layout)
  bf16x8 qa[6];
  {
    int qrow = n0 + l15; if (qrow >= nN) qrow = nN - 1;
    const ushort* qp = &qtb[(size_t)qrow * 192];
    #pragma unroll
    for (int s = 0; s < 6; ++s) qa[s] = *(const bf16x8*)&qp[s * 32 + lh * 8];
  }
  // per-wave node accumulators (wave owns nodes n0+wid*4 .. +3)
  float ps[4] = {};
  float4 pv[4] = {{0,0,0,0},{0,0,0,0},{0,0,0,0},{0,0,0,0}};
  float2 pe[4] = {{0,0},{0,0},{0,0},{0,0}};
  for (int cbeg = tbeg; cbeg < tend; cbeg += PCHUNK) {
    int cend = cbeg + PCHUNK < tend ? cbeg + PCHUNK : tend;
    if (cbeg > tbeg) __syncthreads();   // protect pbuf reuse across chunks
    // ---- phase 1: logits for the chunk, 16 edges per iteration ----
    for (int e0 = cbeg + wid * 16; e0 < cend; e0 += 64) {
      int idx = e0 + l15; if (idx >= cend) idx = cend - 1;
      int sd = csr_sd[idx];
      int src = sd & 0xFFFF, dl = sd >> 16;
      f32x4 acc = {};
      const ushort* krow = &kb[(size_t)src * 128];
      #pragma unroll
      for (int s = 0; s < 4; ++s)
        acc = __builtin_amdgcn_mfma_f32_16x16x32_bf16(
            qa[s], *(const bf16x8*)&krow[s * 32 + lh * 8], acc, 0, 0, 0);
      if (EAP) {
        const ushort* erow = &eaP[(size_t)idx * DE];
        acc = __builtin_amdgcn_mfma_f32_16x16x32_bf16(
            qa[4], *(const bf16x8*)&erow[lh * 8], acc, 0, 0, 0);
        acc = __builtin_amdgcn_mfma_f32_16x16x32_bf16(
            qa[5], *(const bf16x8*)&erow[32 + lh * 8], acc, 0, 0, 0);
      } else {
        int eid = csr_eid[idx];
        #pragma unroll
        for (int s = 0; s < 2; ++s) {
          const float* er = &ea32[(size_t)eid * DE + s * 32 + lh * 8];
          float4 a0 = *(const float4*)er, a1 = *(const float4*)(er + 4);
          bf16x8 ef;
          ef[0] = (short)f2bf(a0.x); ef[1] = (short)f2bf(a0.y);
          ef[2] = (short)f2bf(a0.z); ef[3] = (short)f2bf(a0.w);
          ef[4] = (short)f2bf(a1.x); ef[5] = (short)f2bf(a1.y);
          ef[6] = (short)f2bf(a1.z); ef[7] = (short)f2bf(a1.w);
          acc = __builtin_amdgcn_mfma_f32_16x16x32_bf16(qa[4 + s], ef, acc, 0, 0, 0);
        }
      }
      // extract D[dl[col]][col]: lane holds rows lh*4+r of col l15
      float lg = 0.f;
      #pragma unroll
      for (int r = 0; r < 4; ++r) lg += (lh * 4 + r == dl) ? acc[r] : 0.f;
      lg += __shfl_xor(lg, 16);
      lg += __shfl_xor(lg, 32);
      float p = __expf(lg);                      // no-max softmax (shift-invariant)
      if (lane < 16 && e0 + lane < cend) pbuf[e0 + lane - cbeg] = p;
    }
    __syncthreads();
    // ---- phase 2: PV gather-accumulate for owned nodes over this chunk ----
    #pragma unroll
    for (int t = 0; t < 4; ++t) {
      int nn = n0 + wid * 4 + t;
      if (nn >= nN) continue;
      int nbeg = row_ptr[nn], nend = row_ptr[nn + 1];
      int ibeg = nbeg > cbeg ? nbeg : cbeg;
      int iend = nend < cend ? nend : cend;
      for (int i0 = ibeg; i0 < iend; i0 += 16) {
        int cnt2 = iend - i0; if (cnt2 > 16) cnt2 = 16;
        int li = l15 < cnt2 ? l15 : cnt2 - 1;
        int sdv = csr_sd[i0 + li];
        float pvv = pbuf[i0 + li - cbeg];
        int eidv = 0;
        if (!EAP) eidv = csr_eid[i0 + li];
        #pragma unroll
        for (int j = 0; j < 8; ++j) {
          int e = 2 * j + grp;
          int sd = __shfl(sdv, e);
          float pj = __shfl(pvv, e);
          pj = (e < cnt2) ? pj : 0.f;
          int src = sd & 0xFFFF;
          uint2 vv = *(const uint2*)&vb[(size_t)src * 128 + l5 * 4];
          float2 eav;
          if (EAP) {
            int ec = i0 + (e < cnt2 ? e : cnt2 - 1);
            ushort2 e2 = *(const ushort2*)&eaP[(size_t)ec * DE + l5 * 2];
            eav.x = bf2f(e2.x); eav.y = bf2f(e2.y);
          } else {
            int ej = __shfl(eidv, e);
            eav = *(const float2*)&ea32[(size_t)ej * DE + l5 * 2];
          }
          ps[t] += pj;
          pv[t].x = fmaf(pj, bf2f((ushort)(vv.x & 0xFFFFu)), pv[t].x);
          pv[t].y = fmaf(pj, bf2f((ushort)(vv.x >> 16)),     pv[t].y);
          pv[t].z = fmaf(pj, bf2f((ushort)(vv.y & 0xFFFFu)), pv[t].z);
          pv[t].w = fmaf(pj, bf2f((ushort)(vv.y >> 16)),     pv[t].w);
          pe[t].x = fmaf(pj, eav.x, pe[t].x);
          pe[t].y = fmaf(pj, eav.y, pe[t].y);
        }
      }
    }
  }
  // ---- epilogue per owned node: divide, We matvec, +hr, LN, ReLU, pool ----
  #pragma unroll
  for (int t = 0; t < 4; ++t) {
    int nn = n0 + wid * 4 + t;
    if (nn >= nN) continue;
    float s  = ps[t]   + __shfl_xor(ps[t], 32);
    float vx = pv[t].x + __shfl_xor(pv[t].x, 32);
    float vy = pv[t].y + __shfl_xor(pv[t].y, 32);
    float vz = pv[t].z + __shfl_xor(pv[t].z, 32);
    float vw = pv[t].w + __shfl_xor(pv[t].w, 32);
    float ex = pe[t].x + __shfl_xor(pe[t].x, 32);
    float ey = pe[t].y + __shfl_xor(pe[t].y, 32);
    float inv = (s > 0.f) ? 1.f / s : 0.f;
    float4 o4;
    o4.x = vx * inv; o4.y = vy * inv; o4.z = vz * inv; o4.w = vw * inv;
    ex *= inv; ey *= inv;
    int gb = grp << 5;
    #pragma unroll 8
    for (int c = 0; c < 64; c += 2) {
      float e0v = __shfl(ex, (c >> 1) + gb);
      float e1v = __shfl(ey, (c >> 1) + gb);
      float4 w0 = *(const float4*)&We[c * DEMB + l5 * 4];
      float4 w1 = *(const float4*)&We[(c + 1) * DEMB + l5 * 4];
      o4.x += e0v * w0.x + e1v * w1.x;
      o4.y += e0v * w0.y + e1v * w1.y;
      o4.z += e0v * w0.z + e1v * w1.z;
      o4.w += e0v * w0.w + e1v * w1.w;
    }
    ushort4 hv = *(const ushort4*)&hrb[(size_t)nn * 128 + l5 * 4];
    o4.x += bf2f(hv.x); o4.y += bf2f(hv.y); o4.z += bf2f(hv.z); o4.w += bf2f(hv.w);
    float s1 = o4.x + o4.y + o4.z + o4.w;
    float sq = o4.x*o4.x + o4.y*o4.y + o4.z*o4.z + o4.w*o4.w;
    #pragma unroll
    for (int off = 1; off < 32; off <<= 1) {
      s1 += __shfl_xor(s1, off);
      sq += __shfl_xor(sq, off);
    }
    float mu = s1 * (1.f / 128.f);
    float var = sq * (1.f / 128.f) - mu * mu;
    float rstd = rsqrtf(var + 1e-5f);
    float4 g4 = *(const float4*)&gamma[l5 * 4];
    float4 b4 = *(const float4*)&beta[l5 * 4];
    if (grp == 0) {
      int b = batch[nn];
      atomicAdd(&pool[b * DEMB + l5 * 4 + 0], fmaxf((o4.x - mu) * rstd * g4.x + b4.x, 0.f));
      atomicAdd(&pool[b * DEMB + l5 * 4 + 1], fmaxf((o4.y - mu) * rstd * g4.y + b4.y, 0.f));
      atomicAdd(&pool[b * DEMB + l5 * 4 + 2], fmaxf((o4.z - mu) * rstd * g4.z + b4.z, 0.f));
      atomicAdd(&pool[b * DEMB + l5 * 4 + 3], fmaxf((o4.w - mu) * rstd * g4.w + b4.w, 0.f));
      if (l5 == 0) atomicAdd(&cnt[b], 1.f);
    }
  }
}

__global__ void k_final(const float* __restrict__ pool, const float* __restrict__ cnt,
                        float* __restrict__ out, int total) {
  int i = blockIdx.x * 256 + threadIdx.x;
  if (i < total) out[i] = pool[i] / fmaxf(cnt[i >> 7], 1.f);
}

extern "C" void kernel_launch(void* const* d_in, const int* in_sizes, int n_in,
                              void* d_out, int out_size, void* d_ws, size_t ws_size,
                              hipStream_t stream) {
  const float* x         = (const float*)d_in[0];
  const float* edge_attr = (const float*)d_in[1];
  const int*   edge_index= (const int*)d_in[2];
  const int*   batch     = (const int*)d_in[3];
  const float* W1 = (const float*)d_in[4];
  const float* b1 = (const float*)d_in[5];
  const float* Wq = (const float*)d_in[6];  const float* bq = (const float*)d_in[7];
  const float* Wk = (const float*)d_in[8];  const float* bk = (const float*)d_in[9];
  const float* Wv = (const float*)d_in[10]; const float* bv = (const float*)d_in[11];
  const float* We = (const float*)d_in[12]; const float* be = (const float*)d_in[13];
  const float* Wr = (const float*)d_in[14]; const float* br = (const float*)d_in[15];
  const float* gamma = (const float*)d_in[16];
  const float* beta  = (const float*)d_in[17];
  float* out = (float*)d_out;

  const int nN = in_sizes[0] / DN;       // 50000
  const int nE = in_sizes[1] / DE;       // 1600000

  char* p = (char*)d_ws;
  auto alloc = [&](size_t bytes) -> void* {
    void* r = (void*)p;
    p += (bytes + 255) & ~(size_t)255;
    return r;
  };
  // ---- zeroed region ----
  int*   degi   = (int*)  alloc((size_t)nN * 4);
  int*   cursor = (int*)  alloc((size_t)nN * 4);
  float* pool   = (float*)alloc((size_t)out_size * 4);
  float* cnt    = (float*)alloc(64 * 4);
  size_t zero_bytes = (size_t)(p - (char*)d_ws);
  // ---- non-zeroed ----
  int*    row_ptr = (int*)   alloc((size_t)(nN + 1) * 4);
  float*  dinv    = (float*) alloc((size_t)nN * 4);
  int*    csr_sd  = (int*)   alloc((size_t)nE * 4);
  int*    csr_eid = (int*)   alloc((size_t)nE * 4);
  int*    csr_pos = (int*)   alloc((size_t)nE * 4);
  ushort* Wp1     = (ushort*)alloc((size_t)16 * 4 * 64 * 8 * 2);
  ushort* Wp2     = (ushort*)alloc((size_t)36 * 8 * 64 * 8 * 2);
  float*  bcat    = (float*) alloc(576 * 4);
  ushort* qtb     = (ushort*)alloc((size_t)nN * 192 * 2);
  ushort* hrb     = (ushort*)alloc((size_t)nN * 128 * 2);
  ushort* hb      = (ushort*)alloc((size_t)nN * DHID * 2);
  ushort* xwsb    = (ushort*)alloc((size_t)nN * DHID * 2);  // aliased: xws, then kb|vb
  ushort* kb      = xwsb;                 // xws dead after k_gcn2w; gemm2 writes kb/vb here
  ushort* vb      = xwsb + (size_t)nN * 128;
  size_t base_required = (size_t)(p - (char*)d_ws);
  if (ws_size < base_required) return;
  // optional: edge_attr in CSR order, bf16 (streamed reads in attn)
  ushort* eaP = nullptr;
  size_t eap_bytes = (((size_t)nE * DE * 2) + 255) & ~(size_t)255;
  if (ws_size >= base_required + eap_bytes) eaP = (ushort*)alloc(eap_bytes);

  hipMemsetAsync(d_ws, 0, zero_bytes, stream);

  k_prep1<<<128, 256, 0, stream>>>(W1, Wp1);
  k_prep2<<<576, 256, 0, stream>>>(Wq, Wk, Wv, Wr, We, Wp2);
  k_prep_b<<<3, 256, 0, stream>>>(bq, bk, bv, br, be, We, bcat);
  k_deg<<<(nE + 255) / 256, 256, 0, stream>>>(edge_index, degi, nE);
  k_dinv<<<(nN + 255) / 256, 256, 0, stream>>>(degi, dinv, nN);
  k_scan<<<1, 1024, 0, stream>>>(degi, row_ptr, nN);
  k_scatter<<<(nE + 255) / 256, 256, 0, stream>>>(edge_index, row_ptr, cursor,
                                                  csr_sd, csr_eid, csr_pos, nE);
  if (eaP)
    k_eascatter<<<2048, 256, 0, stream>>>(edge_attr, csr_pos, eaP, nE);
  k_gemm1<<<(nN + 15) / 16, 256, 0, stream>>>(x, Wp1, dinv, xwsb, nN);
  k_gcn2w<<<(nN + 1) / 2, 256, 0, stream>>>(xwsb, row_ptr, csr_sd, dinv, b1, hb, nN);
  k_gemm2<<<(nN + 15) / 16, 256, 0, stream>>>(hb, Wp2, bcat, qtb, kb, vb, hrb, nN);
  {
    int tiles = (nN + 15) / 16;
    if (eaP)
      k_attnT<1><<<tiles, 256, 0, stream>>>(qtb, kb, vb, hrb, eaP, edge_attr, csr_sd,
                                            csr_eid, row_ptr, batch, We, gamma, beta,
                                            pool, cnt, nN);
    else
      k_attnT<0><<<tiles, 256, 0, stream>>>(qtb, kb, vb, hrb, eaP, edge_attr, csr_sd,
                                            csr_eid, row_ptr, batch, We, gamma, beta,
                                            pool, cnt, nN);
  }
  k_final<<<(out_size + 255) / 256, 256, 0, stream>>>(pool, cnt, out, out_size);
}

// Round 9
// 1056.896 us; speedup vs baseline: 2.1277x; 1.1210x over previous
//
#include <hip/hip_runtime.h>

typedef short bf16x8 __attribute__((ext_vector_type(8)));
typedef float f32x4 __attribute__((ext_vector_type(4)));

#define DN 128
#define DE 64
#define DEMB 128
#define DHID 256
#define SCALE 0.08838834764831845f  // 1/sqrt(128)

__device__ __forceinline__ ushort f2bf(float f) {
  unsigned u = __float_as_uint(f);
  return (ushort)((u + 0x7FFFu + ((u >> 16) & 1u)) >> 16);  // RNE
}
__device__ __forceinline__ float bf2f(ushort u) {
  return __uint_as_float((unsigned)u << 16);
}

// ---------- weight pack for GEMM1: W1[128][256] -> frag order, bf16 ----------
__global__ void k_prep1(const float* __restrict__ W1, ushort* __restrict__ Wp1) {
  int idx = blockIdx.x * 256 + threadIdx.x;
  if (idx >= 16 * 4 * 64 * 8) return;
  int j = idx & 7, lane = (idx >> 3) & 63, s = (idx >> 9) & 3, t = idx >> 11;
  int k = s * 32 + (lane >> 4) * 8 + j;
  int c = t * 16 + (lane & 15);
  Wp1[idx] = f2bf(W1[k * DHID + c]);
}

// ---------- weight pack for GEMM2: Wcat[256][576] = [Wq*s | Wk | Wv | Wr | (Wq@We^T)*s] ----------
__global__ void k_prep2(const float* __restrict__ Wq, const float* __restrict__ Wk,
                        const float* __restrict__ Wv, const float* __restrict__ Wr,
                        const float* __restrict__ We, ushort* __restrict__ Wp2) {
  int idx = blockIdx.x * 256 + threadIdx.x;
  if (idx >= 36 * 8 * 64 * 8) return;
  int j = idx & 7, lane = (idx >> 3) & 63, s = (idx >> 9) & 7, t = idx >> 12;
  int k = s * 32 + (lane >> 4) * 8 + j;
  int c = t * 16 + (lane & 15);
  float v;
  if (c < 128)       v = Wq[k * DEMB + c] * SCALE;
  else if (c < 256)  v = Wk[k * DEMB + (c - 128)];
  else if (c < 384)  v = Wv[k * DEMB + (c - 256)];
  else if (c < 512)  v = Wr[k * DEMB + (c - 384)];
  else {
    int cc = c - 512;
    float a = 0.f;
    for (int u = 0; u < DEMB; ++u) a += Wq[k * DEMB + u] * We[cc * DEMB + u];
    v = a * SCALE;
  }
  Wp2[idx] = f2bf(v);
}

__global__ void k_prep_b(const float* __restrict__ bq, const float* __restrict__ bk,
                         const float* __restrict__ bv, const float* __restrict__ br,
                         const float* __restrict__ be, const float* __restrict__ We,
                         float* __restrict__ bcat) {
  int j = blockIdx.x * 256 + threadIdx.x;
  if (j >= 576) return;
  float v;
  if (j < 128)       v = bq[j] * SCALE;
  else if (j < 256)  v = bk[j - 128] + be[j - 128];
  else if (j < 384)  v = bv[j - 256] + be[j - 256];
  else if (j < 512)  v = br[j - 384];
  else {
    int cc = j - 512;
    float a = 0.f;
    for (int u = 0; u < DEMB; ++u) a += bq[u] * We[cc * DEMB + u];
    v = a * SCALE;
  }
  bcat[j] = v;
}

// ---------- weight pack for EWE GEMM: We[64][128] -> frag order, bf16 ----------
__global__ void k_prep3(const float* __restrict__ We, ushort* __restrict__ Wp3) {
  int idx = blockIdx.x * 256 + threadIdx.x;
  if (idx >= 8 * 2 * 64 * 8) return;
  int j = idx & 7, lane = (idx >> 3) & 63, s = (idx >> 9) & 1, t = idx >> 10;
  int k = s * 32 + (lane >> 4) * 8 + j;
  int c = t * 16 + (lane & 15);
  Wp3[idx] = f2bf(We[k * DEMB + c]);
}

// ---------- CSR build ----------
__global__ void k_deg(const int* __restrict__ ei, int* __restrict__ degi, int nE) {
  int e = blockIdx.x * 256 + threadIdx.x;
  if (e < nE) atomicAdd(&degi[ei[nE + e]], 1);
}

__global__ void k_dinv(const int* __restrict__ degi, float* __restrict__ dinv, int nN) {
  int n = blockIdx.x * 256 + threadIdx.x;
  if (n < nN) dinv[n] = rsqrtf(1.0f + (float)degi[n]);
}

__global__ __launch_bounds__(1024) void k_scan(const int* __restrict__ degi,
                                               int* __restrict__ row_ptr, int n) {
  __shared__ int wsum[16];
  __shared__ int carry_s;
  int lane = threadIdx.x & 63, wid = threadIdx.x >> 6;
  if (threadIdx.x == 0) carry_s = 0;
  __syncthreads();
  for (int base = 0; base < n; base += 1024) {
    int i = base + threadIdx.x;
    int v = (i < n) ? degi[i] : 0;
    int sc = v;
    #pragma unroll
    for (int off = 1; off < 64; off <<= 1) {
      int t = __shfl_up(sc, off);
      if (lane >= off) sc += t;
    }
    if (lane == 63) wsum[wid] = sc;
    int carry0 = carry_s;
    __syncthreads();
    if (wid == 0) {
      int w = (lane < 16) ? wsum[lane] : 0;
      int swc = w;
      #pragma unroll
      for (int off = 1; off < 16; off <<= 1) {
        int t = __shfl_up(swc, off);
        if (lane >= off) swc += t;
      }
      if (lane < 16) wsum[lane] = swc - w;
      if (lane == 15) carry_s = carry0 + swc;
    }
    __syncthreads();
    if (i < n) row_ptr[i] = carry0 + wsum[wid] + sc - v;
    __syncthreads();
  }
  if (threadIdx.x == 0) row_ptr[n] = carry_s;
}

__global__ void k_scatter(const int* __restrict__ ei, const int* __restrict__ row_ptr,
                          int* __restrict__ cursor, int2* __restrict__ csr_se, int nE) {
  int e = blockIdx.x * 256 + threadIdx.x;
  if (e >= nE) return;
  int dst = ei[nE + e];
  int pos = row_ptr[dst] + atomicAdd(&cursor[dst], 1);
  csr_se[pos] = make_int2(ei[e], e);
}

// ---------- GEMM1 (MFMA bf16): xwsb[n][256] = bf16( (x @ W1) * dinv[n] ) ----------
__global__ __launch_bounds__(256) void k_gemm1(const float* __restrict__ x,
                                               const ushort* __restrict__ Wp1,
                                               const float* __restrict__ dinv,
                                               ushort* __restrict__ xwsb, int nN) {
  int lane = threadIdx.x & 63, wave = threadIdx.x >> 6;
  int l15 = lane & 15, lh = lane >> 4;
  int m0 = blockIdx.x * 16;
  int rowa = m0 + l15; if (rowa >= nN) rowa = nN - 1;
  f32x4 acc[4] = {};
  for (int s = 0; s < 4; ++s) {
    const float* ap = &x[(size_t)rowa * DN + s * 32 + lh * 8];
    float4 a0 = *(const float4*)ap;
    float4 a1 = *(const float4*)(ap + 4);
    bf16x8 af;
    af[0] = (short)f2bf(a0.x); af[1] = (short)f2bf(a0.y);
    af[2] = (short)f2bf(a0.z); af[3] = (short)f2bf(a0.w);
    af[4] = (short)f2bf(a1.x); af[5] = (short)f2bf(a1.y);
    af[6] = (short)f2bf(a1.z); af[7] = (short)f2bf(a1.w);
    #pragma unroll
    for (int tt = 0; tt < 4; ++tt) {
      int t = wave * 4 + tt;
      bf16x8 bf = *(const bf16x8*)&Wp1[((t * 4 + s) * 64 + lane) * 8];
      acc[tt] = __builtin_amdgcn_mfma_f32_16x16x32_bf16(af, bf, acc[tt], 0, 0, 0);
    }
  }
  #pragma unroll
  for (int tt = 0; tt < 4; ++tt) {
    int c = (wave * 4 + tt) * 16 + l15;
    #pragma unroll
    for (int r = 0; r < 4; ++r) {
      int row = m0 + lh * 4 + r;
      if (row < nN) xwsb[(size_t)row * DHID + c] = f2bf(acc[tt][r] * dinv[row]);
    }
  }
}

// ---------- GEMM2 (MFMA bf16): emits qwb[192]=[q*s|wqe*s], kb[128], vb[128], hrb[128] ----------
__global__ __launch_bounds__(256) void k_gemm2(const ushort* __restrict__ hb,
                                               const ushort* __restrict__ Wp2,
                                               const float* __restrict__ bcat,
                                               ushort* __restrict__ qwb,
                                               ushort* __restrict__ kb,
                                               ushort* __restrict__ vb,
                                               ushort* __restrict__ hrb, int nN) {
  int lane = threadIdx.x & 63, wave = threadIdx.x >> 6;
  int l15 = lane & 15, lh = lane >> 4;
  int m0 = blockIdx.x * 16;
  int rowa = m0 + l15; if (rowa >= nN) rowa = nN - 1;
  f32x4 acc[9] = {};
  for (int s = 0; s < 8; ++s) {
    bf16x8 af = *(const bf16x8*)&hb[(size_t)rowa * DHID + s * 32 + lh * 8];
    #pragma unroll
    for (int tt = 0; tt < 9; ++tt) {
      int t = wave * 9 + tt;
      bf16x8 bf = *(const bf16x8*)&Wp2[((t * 8 + s) * 64 + lane) * 8];
      acc[tt] = __builtin_amdgcn_mfma_f32_16x16x32_bf16(af, bf, acc[tt], 0, 0, 0);
    }
  }
  #pragma unroll
  for (int tt = 0; tt < 9; ++tt) {
    int c = (wave * 9 + tt) * 16 + l15;
    float bc = bcat[c];
    #pragma unroll
    for (int r = 0; r < 4; ++r) {
      int row = m0 + lh * 4 + r;
      if (row >= nN) continue;
      ushort val = f2bf(acc[tt][r] + bc);
      if (c < 128)      qwb[(size_t)row * 192 + c] = val;
      else if (c < 256) kb[(size_t)row * 128 + (c - 128)] = val;
      else if (c < 384) vb[(size_t)row * 128 + (c - 256)] = val;
      else if (c < 512) hrb[(size_t)row * 128 + (c - 384)] = val;
      else              qwb[(size_t)row * 192 + 128 + (c - 512)] = val;
    }
  }
}

// ---------- GCN aggregate: wave per node, 16-lane group per edge, no shfl in loop ----------
__global__ __launch_bounds__(256) void k_gcnE(const ushort* __restrict__ xwsb,
                                              const int2* __restrict__ csr_se,
                                              const int* __restrict__ row_ptr,
                                              const float* __restrict__ dinv,
                                              const float* __restrict__ b1,
                                              ushort* __restrict__ hb, int nN) {
  int lane = threadIdx.x & 63;
  int n = blockIdx.x * 4 + (threadIdx.x >> 6);
  if (n >= nN) return;
  int grp = lane >> 4, l15 = lane & 15;
  int beg = row_ptr[n], end = row_ptr[n + 1];
  float acc[16] = {};
  for (int i0 = beg; i0 < end; i0 += 8) {
    #pragma unroll
    for (int u = 0; u < 2; ++u) {
      int e = i0 + u * 4 + grp;
      bool val = e < end;
      int cl = val ? e : end - 1;
      int src = csr_se[cl].x;                     // same addr across group: HW broadcast
      const ushort* xr = &xwsb[(size_t)src * DHID + l15 * 16];
      uint4 xa = *(const uint4*)xr;
      uint4 xb = *(const uint4*)(xr + 8);
      float w = val ? 1.f : 0.f;
      unsigned qq[8] = {xa.x, xa.y, xa.z, xa.w, xb.x, xb.y, xb.z, xb.w};
      #pragma unroll
      for (int d = 0; d < 8; ++d) {
        acc[2*d]   = fmaf(w, __uint_as_float(qq[d] << 16), acc[2*d]);
        acc[2*d+1] = fmaf(w, __uint_as_float(qq[d] & 0xFFFF0000u), acc[2*d+1]);
      }
    }
  }
  #pragma unroll
  for (int d = 0; d < 16; ++d) {
    acc[d] += __shfl_xor(acc[d], 16);
    acc[d] += __shfl_xor(acc[d], 32);
  }
  if (grp == 0) {
    const ushort* sr = &xwsb[(size_t)n * DHID + l15 * 16];
    uint4 sa = *(const uint4*)sr;
    uint4 sb = *(const uint4*)(sr + 8);
    unsigned sq[8] = {sa.x, sa.y, sa.z, sa.w, sb.x, sb.y, sb.z, sb.w};
    float dn = dinv[n];
    unsigned ov[8];
    #pragma unroll
    for (int d = 0; d < 8; ++d) {
      float blo = b1[l15 * 16 + 2*d], bhi = b1[l15 * 16 + 2*d + 1];
      float lo = __uint_as_float(sq[d] << 16);
      float hi = __uint_as_float(sq[d] & 0xFFFF0000u);
      float v0 = fmaxf((acc[2*d]   + lo) * dn + blo, 0.f);
      float v1 = fmaxf((acc[2*d+1] + hi) * dn + bhi, 0.f);
      ov[d] = (unsigned)f2bf(v0) | ((unsigned)f2bf(v1) << 16);
    }
    uint4 o0 = {ov[0], ov[1], ov[2], ov[3]};
    uint4 o1 = {ov[4], ov[5], ov[6], ov[7]};
    ushort* hr = &hb[(size_t)n * DHID + l15 * 16];
    *(uint4*)hr = o0;
    *(uint4*)(hr + 8) = o1;
  }
}

// ---------- fused attention edge pass: wave per node, group per edge ----------
__global__ __launch_bounds__(256) void k_edge(const ushort* __restrict__ qwb,
                                              const ushort* __restrict__ kb,
                                              const ushort* __restrict__ vb,
                                              const float* __restrict__ ea32,
                                              const int2* __restrict__ csr_se,
                                              const int* __restrict__ row_ptr,
                                              float* __restrict__ sden,
                                              float* __restrict__ vaccf,
                                              ushort* __restrict__ ewb, int nN) {
  int lane = threadIdx.x & 63;
  int n = blockIdx.x * 4 + (threadIdx.x >> 6);
  if (n >= nN) return;
  int grp = lane >> 4, l15 = lane & 15;
  const ushort* qp = &qwb[(size_t)n * 192];
  bf16x8 qv = *(const bf16x8*)&qp[l15 * 8];       // q dims l15*8..+7 (pre-scaled)
  ushort4 wv = *(const ushort4*)&qp[128 + l15 * 4]; // wqe dims l15*4..+3 (pre-scaled)
  float q[8];
  #pragma unroll
  for (int d = 0; d < 8; ++d) q[d] = bf2f((ushort)qv[d]);
  float w0 = bf2f(wv.x), w1 = bf2f(wv.y), w2 = bf2f(wv.z), w3 = bf2f(wv.w);
  float s_acc = 0.f;
  float av[8] = {};
  float ae[4] = {};
  int beg = row_ptr[n], end = row_ptr[n + 1];
  for (int i0 = beg; i0 < end; i0 += 8) {
    #pragma unroll
    for (int u = 0; u < 2; ++u) {
      int e = i0 + u * 4 + grp;
      bool val = e < end;
      int cl = val ? e : end - 1;
      int2 se = csr_se[cl];                       // same addr across group: HW broadcast
      bf16x8 kv8 = *(const bf16x8*)&kb[(size_t)se.x * 128 + l15 * 8];
      bf16x8 vv8 = *(const bf16x8*)&vb[(size_t)se.x * 128 + l15 * 8];
      float4 eav = *(const float4*)&ea32[(size_t)se.y * DE + l15 * 4];
      float dot = w0 * eav.x + w1 * eav.y + w2 * eav.z + w3 * eav.w;
      #pragma unroll
      for (int d = 0; d < 8; ++d) dot = fmaf(q[d], bf2f((ushort)kv8[d]), dot);
      dot += __shfl_xor(dot, 1);
      dot += __shfl_xor(dot, 2);
      dot += __shfl_xor(dot, 4);
      dot += __shfl_xor(dot, 8);                  // 16-lane group reduce
      float p = val ? __expf(dot) : 0.f;          // no-max softmax (shift-invariant)
      s_acc += p;
      #pragma unroll
      for (int d = 0; d < 8; ++d) av[d] = fmaf(p, bf2f((ushort)vv8[d]), av[d]);
      ae[0] = fmaf(p, eav.x, ae[0]);
      ae[1] = fmaf(p, eav.y, ae[1]);
      ae[2] = fmaf(p, eav.z, ae[2]);
      ae[3] = fmaf(p, eav.w, ae[3]);
    }
  }
  s_acc += __shfl_xor(s_acc, 16); s_acc += __shfl_xor(s_acc, 32);
  #pragma unroll
  for (int d = 0; d < 8; ++d) {
    av[d] += __shfl_xor(av[d], 16);
    av[d] += __shfl_xor(av[d], 32);
  }
  #pragma unroll
  for (int d = 0; d < 4; ++d) {
    ae[d] += __shfl_xor(ae[d], 16);
    ae[d] += __shfl_xor(ae[d], 32);
  }
  if (grp == 0) {
    if (l15 == 0) sden[n] = s_acc;
    float4 o0 = {av[0], av[1], av[2], av[3]};
    float4 o1 = {av[4], av[5], av[6], av[7]};
    float* vr = &vaccf[(size_t)n * 128 + l15 * 8];
    *(float4*)vr = o0;
    *(float4*)(vr + 4) = o1;
    ushort4 eo;
    eo.x = f2bf(ae[0]); eo.y = f2bf(ae[1]); eo.z = f2bf(ae[2]); eo.w = f2bf(ae[3]);
    *(ushort4*)&ewb[(size_t)n * DE + l15 * 4] = eo;
  }
}

// ---------- EWE GEMM (MFMA bf16): ewout[nN,128] = ewb[nN,64] @ We[64,128] ----------
__global__ __launch_bounds__(256) void k_ewe(const ushort* __restrict__ ewb,
                                             const ushort* __restrict__ Wp3,
                                             float* __restrict__ ewout, int nN) {
  int lane = threadIdx.x & 63, wave = threadIdx.x >> 6;
  int l15 = lane & 15, lh = lane >> 4;
  int m0 = blockIdx.x * 16;
  int rowa = m0 + l15; if (rowa >= nN) rowa = nN - 1;
  f32x4 acc[2] = {};
  #pragma unroll
  for (int s = 0; s < 2; ++s) {
    bf16x8 af = *(const bf16x8*)&ewb[(size_t)rowa * DE + s * 32 + lh * 8];
    #pragma unroll
    for (int tt = 0; tt < 2; ++tt) {
      int t = wave * 2 + tt;
      bf16x8 bf = *(const bf16x8*)&Wp3[((t * 2 + s) * 64 + lane) * 8];
      acc[tt] = __builtin_amdgcn_mfma_f32_16x16x32_bf16(af, bf, acc[tt], 0, 0, 0);
    }
  }
  #pragma unroll
  for (int tt = 0; tt < 2; ++tt) {
    int c = (wave * 2 + tt) * 16 + l15;
    #pragma unroll
    for (int r = 0; r < 4; ++r) {
      int row = m0 + lh * 4 + r;
      if (row < nN) ewout[(size_t)row * 128 + c] = acc[tt][r];
    }
  }
}

// ---------- finalize: o = (vacc + ewout)/s + hr, LN, ReLU, pool; 2 nodes/wave ----------
__global__ __launch_bounds__(256) void k_fin(const float* __restrict__ sden,
                                             const float* __restrict__ vaccf,
                                             const float* __restrict__ ewout,
                                             const ushort* __restrict__ hrb,
                                             const int* __restrict__ batch,
                                             const float* __restrict__ gamma,
                                             const float* __restrict__ beta,
                                             float* __restrict__ pool,
                                             float* __restrict__ cnt, int nN) {
  int lane = threadIdx.x & 63, grp = lane >> 5, l5 = lane & 31;
  int n = blockIdx.x * 8 + (threadIdx.x >> 6) * 2 + grp;
  if (n >= nN) return;
  float s = sden[n];
  float inv = (s > 0.f) ? 1.f / s : 0.f;
  float4 v4 = *(const float4*)&vaccf[(size_t)n * 128 + l5 * 4];
  float4 w4 = *(const float4*)&ewout[(size_t)n * 128 + l5 * 4];
  ushort4 hv = *(const ushort4*)&hrb[(size_t)n * 128 + l5 * 4];
  float4 o4;
  o4.x = (v4.x + w4.x) * inv + bf2f(hv.x);
  o4.y = (v4.y + w4.y) * inv + bf2f(hv.y);
  o4.z = (v4.z + w4.z) * inv + bf2f(hv.z);
  o4.w = (v4.w + w4.w) * inv + bf2f(hv.w);
  float s1 = o4.x + o4.y + o4.z + o4.w;
  float sq = o4.x*o4.x + o4.y*o4.y + o4.z*o4.z + o4.w*o4.w;
  #pragma unroll
  for (int off = 1; off < 32; off <<= 1) {
    s1 += __shfl_xor(s1, off);
    sq += __shfl_xor(sq, off);
  }
  float mu = s1 * (1.f / 128.f);
  float var = sq * (1.f / 128.f) - mu * mu;
  float rstd = rsqrtf(var + 1e-5f);
  float4 g4 = *(const float4*)&gamma[l5 * 4];
  float4 b4 = *(const float4*)&beta[l5 * 4];
  int b = batch[n];
  atomicAdd(&pool[b * DEMB + l5 * 4 + 0], fmaxf((o4.x - mu) * rstd * g4.x + b4.x, 0.f));
  atomicAdd(&pool[b * DEMB + l5 * 4 + 1], fmaxf((o4.y - mu) * rstd * g4.y + b4.y, 0.f));
  atomicAdd(&pool[b * DEMB + l5 * 4 + 2], fmaxf((o4.z - mu) * rstd * g4.z + b4.z, 0.f));
  atomicAdd(&pool[b * DEMB + l5 * 4 + 3], fmaxf((o4.w - mu) * rstd * g4.w + b4.w, 0.f));
  if (l5 == 0) atomicAdd(&cnt[b], 1.f);
}

__global__ void k_final(const float* __restrict__ pool, const float* __restrict__ cnt,
                        float* __restrict__ out, int total) {
  int i = blockIdx.x * 256 + threadIdx.x;
  if (i < total) out[i] = pool[i] / fmaxf(cnt[i >> 7], 1.f);
}

extern "C" void kernel_launch(void* const* d_in, const int* in_sizes, int n_in,
                              void* d_out, int out_size, void* d_ws, size_t ws_size,
                              hipStream_t stream) {
  const float* x         = (const float*)d_in[0];
  const float* edge_attr = (const float*)d_in[1];
  const int*   edge_index= (const int*)d_in[2];
  const int*   batch     = (const int*)d_in[3];
  const float* W1 = (const float*)d_in[4];
  const float* b1 = (const float*)d_in[5];
  const float* Wq = (const float*)d_in[6];  const float* bq = (const float*)d_in[7];
  const float* Wk = (const float*)d_in[8];  const float* bk = (const float*)d_in[9];
  const float* Wv = (const float*)d_in[10]; const float* bv = (const float*)d_in[11];
  const float* We = (const float*)d_in[12]; const float* be = (const float*)d_in[13];
  const float* Wr = (const float*)d_in[14]; const float* br = (const float*)d_in[15];
  const float* gamma = (const float*)d_in[16];
  const float* beta  = (const float*)d_in[17];
  float* out = (float*)d_out;

  const int nN = in_sizes[0] / DN;       // 50000
  const int nE = in_sizes[1] / DE;       // 1600000

  char* p = (char*)d_ws;
  auto alloc = [&](size_t bytes) -> void* {
    void* r = (void*)p;
    p += (bytes + 255) & ~(size_t)255;
    return r;
  };
  // ---- zeroed region ----
  int*   degi   = (int*)  alloc((size_t)nN * 4);
  int*   cursor = (int*)  alloc((size_t)nN * 4);
  float* pool   = (float*)alloc((size_t)out_size * 4);
  float* cnt    = (float*)alloc(64 * 4);
  size_t zero_bytes = (size_t)(p - (char*)d_ws);
  // ---- non-zeroed ----
  int*    row_ptr = (int*)   alloc((size_t)(nN + 1) * 4);
  float*  dinv    = (float*) alloc((size_t)nN * 4);
  int2*   csr_se  = (int2*)  alloc((size_t)nE * 8);
  ushort* Wp1     = (ushort*)alloc((size_t)16 * 4 * 64 * 8 * 2);
  ushort* Wp2     = (ushort*)alloc((size_t)36 * 8 * 64 * 8 * 2);
  ushort* Wp3     = (ushort*)alloc((size_t)8 * 2 * 64 * 8 * 2);
  float*  bcat    = (float*) alloc(576 * 4);
  ushort* qwb     = (ushort*)alloc((size_t)nN * 192 * 2);
  ushort* hrb     = (ushort*)alloc((size_t)nN * 128 * 2);
  ushort* hb      = (ushort*)alloc((size_t)nN * DHID * 2);
  ushort* xwsb    = (ushort*)alloc((size_t)nN * DHID * 2);  // aliased: xws, then kb|vb
  ushort* kb      = xwsb;                 // xws dead after k_gcnE; gemm2 writes kb/vb here
  ushort* vb      = xwsb + (size_t)nN * 128;
  float*  sden    = (float*) alloc((size_t)nN * 4);
  float*  vaccf   = (float*) alloc((size_t)nN * 128 * 4);
  ushort* ewb     = (ushort*)alloc((size_t)nN * DE * 2);
  float*  ewout   = (float*) alloc((size_t)nN * 128 * 4);
  size_t required = (size_t)(p - (char*)d_ws);
  if (ws_size < required) return;

  hipMemsetAsync(d_ws, 0, zero_bytes, stream);

  k_prep1<<<128, 256, 0, stream>>>(W1, Wp1);
  k_prep2<<<576, 256, 0, stream>>>(Wq, Wk, Wv, Wr, We, Wp2);
  k_prep_b<<<3, 256, 0, stream>>>(bq, bk, bv, br, be, We, bcat);
  k_prep3<<<32, 256, 0, stream>>>(We, Wp3);
  k_deg<<<(nE + 255) / 256, 256, 0, stream>>>(edge_index, degi, nE);
  k_dinv<<<(nN + 255) / 256, 256, 0, stream>>>(degi, dinv, nN);
  k_scan<<<1, 1024, 0, stream>>>(degi, row_ptr, nN);
  k_scatter<<<(nE + 255) / 256, 256, 0, stream>>>(edge_index, row_ptr, cursor,
                                                  csr_se, nE);
  k_gemm1<<<(nN + 15) / 16, 256, 0, stream>>>(x, Wp1, dinv, xwsb, nN);
  k_gcnE<<<(nN + 3) / 4, 256, 0, stream>>>(xwsb, csr_se, row_ptr, dinv, b1, hb, nN);
  k_gemm2<<<(nN + 15) / 16, 256, 0, stream>>>(hb, Wp2, bcat, qwb, kb, vb, hrb, nN);
  k_edge<<<(nN + 3) / 4, 256, 0, stream>>>(qwb, kb, vb, edge_attr, csr_se, row_ptr,
                                           sden, vaccf, ewb, nN);
  k_ewe<<<(nN + 15) / 16, 256, 0, stream>>>(ewb, Wp3, ewout, nN);
  k_fin<<<(nN + 7) / 8, 256, 0, stream>>>(sden, vaccf, ewout, hrb, batch,
                                          gamma, beta, pool, cnt, nN);
  k_final<<<(out_size + 255) / 256, 256, 0, stream>>>(pool, cnt, out, out_size);
}

// Round 10
// 680.772 us; speedup vs baseline: 3.3033x; 1.5525x over previous
//
#include <hip/hip_runtime.h>

typedef short bf16x8 __attribute__((ext_vector_type(8)));
typedef float f32x4 __attribute__((ext_vector_type(4)));

#define DN 128
#define DE 64
#define DEMB 128
#define DHID 256
#define SCALE 0.08838834764831845f  // 1/sqrt(128)

__device__ __forceinline__ ushort f2bf(float f) {
  unsigned u = __float_as_uint(f);
  return (ushort)((u + 0x7FFFu + ((u >> 16) & 1u)) >> 16);  // RNE
}
__device__ __forceinline__ float bf2f(ushort u) {
  return __uint_as_float((unsigned)u << 16);
}

// ---------- weight pack for GEMM1: W1[128][256] -> frag order, bf16 ----------
__global__ void k_prep1(const float* __restrict__ W1, ushort* __restrict__ Wp1) {
  int idx = blockIdx.x * 256 + threadIdx.x;
  if (idx >= 16 * 4 * 64 * 8) return;
  int j = idx & 7, lane = (idx >> 3) & 63, s = (idx >> 9) & 3, t = idx >> 11;
  int k = s * 32 + (lane >> 4) * 8 + j;
  int c = t * 16 + (lane & 15);
  Wp1[idx] = f2bf(W1[k * DHID + c]);
}

// ---------- weight pack for GEMM2: Wcat[256][576] = [Wq*s | Wk | Wv | Wr | (Wq@We^T)*s] ----------
__global__ void k_prep2(const float* __restrict__ Wq, const float* __restrict__ Wk,
                        const float* __restrict__ Wv, const float* __restrict__ Wr,
                        const float* __restrict__ We, ushort* __restrict__ Wp2) {
  int idx = blockIdx.x * 256 + threadIdx.x;
  if (idx >= 36 * 8 * 64 * 8) return;
  int j = idx & 7, lane = (idx >> 3) & 63, s = (idx >> 9) & 7, t = idx >> 12;
  int k = s * 32 + (lane >> 4) * 8 + j;
  int c = t * 16 + (lane & 15);
  float v;
  if (c < 128)       v = Wq[k * DEMB + c] * SCALE;
  else if (c < 256)  v = Wk[k * DEMB + (c - 128)];
  else if (c < 384)  v = Wv[k * DEMB + (c - 256)];
  else if (c < 512)  v = Wr[k * DEMB + (c - 384)];
  else {
    int cc = c - 512;
    float a = 0.f;
    for (int u = 0; u < DEMB; ++u) a += Wq[k * DEMB + u] * We[cc * DEMB + u];
    v = a * SCALE;
  }
  Wp2[idx] = f2bf(v);
}

__global__ void k_prep_b(const float* __restrict__ bq, const float* __restrict__ bk,
                         const float* __restrict__ bv, const float* __restrict__ br,
                         const float* __restrict__ be, const float* __restrict__ We,
                         float* __restrict__ bcat) {
  int j = blockIdx.x * 256 + threadIdx.x;
  if (j >= 576) return;
  float v;
  if (j < 128)       v = bq[j] * SCALE;
  else if (j < 256)  v = bk[j - 128] + be[j - 128];
  else if (j < 384)  v = bv[j - 256] + be[j - 256];
  else if (j < 512)  v = br[j - 384];
  else {
    int cc = j - 512;
    float a = 0.f;
    for (int u = 0; u < DEMB; ++u) a += bq[u] * We[cc * DEMB + u];
    v = a * SCALE;
  }
  bcat[j] = v;
}

// ---------- weight pack for EWE GEMM: We[64][128] -> frag order, bf16 ----------
__global__ void k_prep3(const float* __restrict__ We, ushort* __restrict__ Wp3) {
  int idx = blockIdx.x * 256 + threadIdx.x;
  if (idx >= 8 * 2 * 64 * 8) return;
  int j = idx & 7, lane = (idx >> 3) & 63, s = (idx >> 9) & 1, t = idx >> 10;
  int k = s * 32 + (lane >> 4) * 8 + j;
  int c = t * 16 + (lane & 15);
  Wp3[idx] = f2bf(We[k * DEMB + c]);
}

// ---------- CSR build ----------
__global__ void k_deg(const int* __restrict__ ei, int* __restrict__ degi, int nE) {
  int e = blockIdx.x * 256 + threadIdx.x;
  if (e < nE) atomicAdd(&degi[ei[nE + e]], 1);
}

__global__ void k_dinv(const int* __restrict__ degi, float* __restrict__ dinv, int nN) {
  int n = blockIdx.x * 256 + threadIdx.x;
  if (n < nN) dinv[n] = rsqrtf(1.0f + (float)degi[n]);
}

__global__ __launch_bounds__(1024) void k_scan(const int* __restrict__ degi,
                                               int* __restrict__ row_ptr, int n) {
  __shared__ int wsum[16];
  __shared__ int carry_s;
  int lane = threadIdx.x & 63, wid = threadIdx.x >> 6;
  if (threadIdx.x == 0) carry_s = 0;
  __syncthreads();
  for (int base = 0; base < n; base += 1024) {
    int i = base + threadIdx.x;
    int v = (i < n) ? degi[i] : 0;
    int sc = v;
    #pragma unroll
    for (int off = 1; off < 64; off <<= 1) {
      int t = __shfl_up(sc, off);
      if (lane >= off) sc += t;
    }
    if (lane == 63) wsum[wid] = sc;
    int carry0 = carry_s;
    __syncthreads();
    if (wid == 0) {
      int w = (lane < 16) ? wsum[lane] : 0;
      int swc = w;
      #pragma unroll
      for (int off = 1; off < 16; off <<= 1) {
        int t = __shfl_up(swc, off);
        if (lane >= off) swc += t;
      }
      if (lane < 16) wsum[lane] = swc - w;
      if (lane == 15) carry_s = carry0 + swc;
    }
    __syncthreads();
    if (i < n) row_ptr[i] = carry0 + wsum[wid] + sc - v;
    __syncthreads();
  }
  if (threadIdx.x == 0) row_ptr[n] = carry_s;
}

__global__ void k_scatter(const int* __restrict__ ei, const int* __restrict__ row_ptr,
                          int* __restrict__ cursor, int2* __restrict__ csr_se, int nE) {
  int e = blockIdx.x * 256 + threadIdx.x;
  if (e >= nE) return;
  int dst = ei[nE + e];
  int pos = row_ptr[dst] + atomicAdd(&cursor[dst], 1);
  csr_se[pos] = make_int2(ei[e], e);
}

// ---------- graph segment boundaries from sorted batch ----------
__global__ void k_gbounds(const int* __restrict__ batch, int* __restrict__ gstart,
                          int nN, int B) {
  int n = blockIdx.x * 256 + threadIdx.x;
  if (n >= nN) return;
  int b = batch[n];
  if (n == 0) {
    for (int g = 0; g <= b; ++g) gstart[g] = 0;
  } else {
    int pb = batch[n - 1];
    for (int g = pb + 1; g <= b; ++g) gstart[g] = n;
  }
  if (n == nN - 1) {
    for (int g = b + 1; g <= B; ++g) gstart[g] = nN;
  }
}

// ---------- GEMM1 (MFMA bf16): xwsb[n][256] = bf16( (x @ W1) * dinv[n] ) ----------
__global__ __launch_bounds__(256) void k_gemm1(const float* __restrict__ x,
                                               const ushort* __restrict__ Wp1,
                                               const float* __restrict__ dinv,
                                               ushort* __restrict__ xwsb, int nN) {
  int lane = threadIdx.x & 63, wave = threadIdx.x >> 6;
  int l15 = lane & 15, lh = lane >> 4;
  int m0 = blockIdx.x * 16;
  int rowa = m0 + l15; if (rowa >= nN) rowa = nN - 1;
  f32x4 acc[4] = {};
  for (int s = 0; s < 4; ++s) {
    const float* ap = &x[(size_t)rowa * DN + s * 32 + lh * 8];
    float4 a0 = *(const float4*)ap;
    float4 a1 = *(const float4*)(ap + 4);
    bf16x8 af;
    af[0] = (short)f2bf(a0.x); af[1] = (short)f2bf(a0.y);
    af[2] = (short)f2bf(a0.z); af[3] = (short)f2bf(a0.w);
    af[4] = (short)f2bf(a1.x); af[5] = (short)f2bf(a1.y);
    af[6] = (short)f2bf(a1.z); af[7] = (short)f2bf(a1.w);
    #pragma unroll
    for (int tt = 0; tt < 4; ++tt) {
      int t = wave * 4 + tt;
      bf16x8 bf = *(const bf16x8*)&Wp1[((t * 4 + s) * 64 + lane) * 8];
      acc[tt] = __builtin_amdgcn_mfma_f32_16x16x32_bf16(af, bf, acc[tt], 0, 0, 0);
    }
  }
  #pragma unroll
  for (int tt = 0; tt < 4; ++tt) {
    int c = (wave * 4 + tt) * 16 + l15;
    #pragma unroll
    for (int r = 0; r < 4; ++r) {
      int row = m0 + lh * 4 + r;
      if (row < nN) xwsb[(size_t)row * DHID + c] = f2bf(acc[tt][r] * dinv[row]);
    }
  }
}

// ---------- GEMM2 (MFMA bf16): emits qwb[192]=[q*s|wqe*s], kb[128], vb[128], hrb[128] ----------
__global__ __launch_bounds__(256) void k_gemm2(const ushort* __restrict__ hb,
                                               const ushort* __restrict__ Wp2,
                                               const float* __restrict__ bcat,
                                               ushort* __restrict__ qwb,
                                               ushort* __restrict__ kb,
                                               ushort* __restrict__ vb,
                                               ushort* __restrict__ hrb, int nN) {
  int lane = threadIdx.x & 63, wave = threadIdx.x >> 6;
  int l15 = lane & 15, lh = lane >> 4;
  int m0 = blockIdx.x * 16;
  int rowa = m0 + l15; if (rowa >= nN) rowa = nN - 1;
  f32x4 acc[9] = {};
  for (int s = 0; s < 8; ++s) {
    bf16x8 af = *(const bf16x8*)&hb[(size_t)rowa * DHID + s * 32 + lh * 8];
    #pragma unroll
    for (int tt = 0; tt < 9; ++tt) {
      int t = wave * 9 + tt;
      bf16x8 bf = *(const bf16x8*)&Wp2[((t * 8 + s) * 64 + lane) * 8];
      acc[tt] = __builtin_amdgcn_mfma_f32_16x16x32_bf16(af, bf, acc[tt], 0, 0, 0);
    }
  }
  #pragma unroll
  for (int tt = 0; tt < 9; ++tt) {
    int c = (wave * 9 + tt) * 16 + l15;
    float bc = bcat[c];
    #pragma unroll
    for (int r = 0; r < 4; ++r) {
      int row = m0 + lh * 4 + r;
      if (row >= nN) continue;
      ushort val = f2bf(acc[tt][r] + bc);
      if (c < 128)      qwb[(size_t)row * 192 + c] = val;
      else if (c < 256) kb[(size_t)row * 128 + (c - 128)] = val;
      else if (c < 384) vb[(size_t)row * 128 + (c - 256)] = val;
      else if (c < 512) hrb[(size_t)row * 128 + (c - 384)] = val;
      else              qwb[(size_t)row * 192 + 128 + (c - 512)] = val;
    }
  }
}

// ---------- GCN aggregate: wave per node, 16-lane group per edge, no shfl in loop ----------
__global__ __launch_bounds__(256) void k_gcnE(const ushort* __restrict__ xwsb,
                                              const int2* __restrict__ csr_se,
                                              const int* __restrict__ row_ptr,
                                              const float* __restrict__ dinv,
                                              const float* __restrict__ b1,
                                              ushort* __restrict__ hb, int nN) {
  int lane = threadIdx.x & 63;
  int n = blockIdx.x * 4 + (threadIdx.x >> 6);
  if (n >= nN) return;
  int grp = lane >> 4, l15 = lane & 15;
  int beg = row_ptr[n], end = row_ptr[n + 1];
  float acc[16] = {};
  for (int i0 = beg; i0 < end; i0 += 8) {
    #pragma unroll
    for (int u = 0; u < 2; ++u) {
      int e = i0 + u * 4 + grp;
      bool val = e < end;
      int cl = val ? e : end - 1;
      int src = csr_se[cl].x;                     // same addr across group: HW broadcast
      const ushort* xr = &xwsb[(size_t)src * DHID + l15 * 16];
      uint4 xa = *(const uint4*)xr;
      uint4 xb = *(const uint4*)(xr + 8);
      float w = val ? 1.f : 0.f;
      unsigned qq[8] = {xa.x, xa.y, xa.z, xa.w, xb.x, xb.y, xb.z, xb.w};
      #pragma unroll
      for (int d = 0; d < 8; ++d) {
        acc[2*d]   = fmaf(w, __uint_as_float(qq[d] << 16), acc[2*d]);
        acc[2*d+1] = fmaf(w, __uint_as_float(qq[d] & 0xFFFF0000u), acc[2*d+1]);
      }
    }
  }
  #pragma unroll
  for (int d = 0; d < 16; ++d) {
    acc[d] += __shfl_xor(acc[d], 16);
    acc[d] += __shfl_xor(acc[d], 32);
  }
  if (grp == 0) {
    const ushort* sr = &xwsb[(size_t)n * DHID + l15 * 16];
    uint4 sa = *(const uint4*)sr;
    uint4 sb = *(const uint4*)(sr + 8);
    unsigned sq[8] = {sa.x, sa.y, sa.z, sa.w, sb.x, sb.y, sb.z, sb.w};
    float dn = dinv[n];
    unsigned ov[8];
    #pragma unroll
    for (int d = 0; d < 8; ++d) {
      float blo = b1[l15 * 16 + 2*d], bhi = b1[l15 * 16 + 2*d + 1];
      float lo = __uint_as_float(sq[d] << 16);
      float hi = __uint_as_float(sq[d] & 0xFFFF0000u);
      float v0 = fmaxf((acc[2*d]   + lo) * dn + blo, 0.f);
      float v1 = fmaxf((acc[2*d+1] + hi) * dn + bhi, 0.f);
      ov[d] = (unsigned)f2bf(v0) | ((unsigned)f2bf(v1) << 16);
    }
    uint4 o0 = {ov[0], ov[1], ov[2], ov[3]};
    uint4 o1 = {ov[4], ov[5], ov[6], ov[7]};
    ushort* hr = &hb[(size_t)n * DHID + l15 * 16];
    *(uint4*)hr = o0;
    *(uint4*)(hr + 8) = o1;
  }
}

// ---------- fused attention edge pass: wave per node, group per edge ----------
__global__ __launch_bounds__(256) void k_edge(const ushort* __restrict__ qwb,
                                              const ushort* __restrict__ kb,
                                              const ushort* __restrict__ vb,
                                              const float* __restrict__ ea32,
                                              const int2* __restrict__ csr_se,
                                              const int* __restrict__ row_ptr,
                                              float* __restrict__ sden,
                                              float* __restrict__ vaccf,
                                              ushort* __restrict__ ewb, int nN) {
  int lane = threadIdx.x & 63;
  int n = blockIdx.x * 4 + (threadIdx.x >> 6);
  if (n >= nN) return;
  int grp = lane >> 4, l15 = lane & 15;
  const ushort* qp = &qwb[(size_t)n * 192];
  bf16x8 qv = *(const bf16x8*)&qp[l15 * 8];       // q dims l15*8..+7 (pre-scaled)
  ushort4 wv = *(const ushort4*)&qp[128 + l15 * 4]; // wqe dims l15*4..+3 (pre-scaled)
  float q[8];
  #pragma unroll
  for (int d = 0; d < 8; ++d) q[d] = bf2f((ushort)qv[d]);
  float w0 = bf2f(wv.x), w1 = bf2f(wv.y), w2 = bf2f(wv.z), w3 = bf2f(wv.w);
  float s_acc = 0.f;
  float av[8] = {};
  float ae[4] = {};
  int beg = row_ptr[n], end = row_ptr[n + 1];
  for (int i0 = beg; i0 < end; i0 += 8) {
    #pragma unroll
    for (int u = 0; u < 2; ++u) {
      int e = i0 + u * 4 + grp;
      bool val = e < end;
      int cl = val ? e : end - 1;
      int2 se = csr_se[cl];                       // same addr across group: HW broadcast
      bf16x8 kv8 = *(const bf16x8*)&kb[(size_t)se.x * 128 + l15 * 8];
      bf16x8 vv8 = *(const bf16x8*)&vb[(size_t)se.x * 128 + l15 * 8];
      float4 eav = *(const float4*)&ea32[(size_t)se.y * DE + l15 * 4];
      float dot = w0 * eav.x + w1 * eav.y + w2 * eav.z + w3 * eav.w;
      #pragma unroll
      for (int d = 0; d < 8; ++d) dot = fmaf(q[d], bf2f((ushort)kv8[d]), dot);
      dot += __shfl_xor(dot, 1);
      dot += __shfl_xor(dot, 2);
      dot += __shfl_xor(dot, 4);
      dot += __shfl_xor(dot, 8);                  // 16-lane group reduce
      float p = val ? __expf(dot) : 0.f;          // no-max softmax (shift-invariant)
      s_acc += p;
      #pragma unroll
      for (int d = 0; d < 8; ++d) av[d] = fmaf(p, bf2f((ushort)vv8[d]), av[d]);
      ae[0] = fmaf(p, eav.x, ae[0]);
      ae[1] = fmaf(p, eav.y, ae[1]);
      ae[2] = fmaf(p, eav.z, ae[2]);
      ae[3] = fmaf(p, eav.w, ae[3]);
    }
  }
  s_acc += __shfl_xor(s_acc, 16); s_acc += __shfl_xor(s_acc, 32);
  #pragma unroll
  for (int d = 0; d < 8; ++d) {
    av[d] += __shfl_xor(av[d], 16);
    av[d] += __shfl_xor(av[d], 32);
  }
  #pragma unroll
  for (int d = 0; d < 4; ++d) {
    ae[d] += __shfl_xor(ae[d], 16);
    ae[d] += __shfl_xor(ae[d], 32);
  }
  if (grp == 0) {
    if (l15 == 0) sden[n] = s_acc;
    float4 o0 = {av[0], av[1], av[2], av[3]};
    float4 o1 = {av[4], av[5], av[6], av[7]};
    float* vr = &vaccf[(size_t)n * 128 + l15 * 8];
    *(float4*)vr = o0;
    *(float4*)(vr + 4) = o1;
    ushort4 eo;
    eo.x = f2bf(ae[0]); eo.y = f2bf(ae[1]); eo.z = f2bf(ae[2]); eo.w = f2bf(ae[3]);
    *(ushort4*)&ewb[(size_t)n * DE + l15 * 4] = eo;
  }
}

// ---------- EWE GEMM (MFMA bf16): ewout[nN,128] = ewb[nN,64] @ We[64,128] ----------
__global__ __launch_bounds__(256) void k_ewe(const ushort* __restrict__ ewb,
                                             const ushort* __restrict__ Wp3,
                                             float* __restrict__ ewout, int nN) {
  int lane = threadIdx.x & 63, wave = threadIdx.x >> 6;
  int l15 = lane & 15, lh = lane >> 4;
  int m0 = blockIdx.x * 16;
  int rowa = m0 + l15; if (rowa >= nN) rowa = nN - 1;
  f32x4 acc[2] = {};
  #pragma unroll
  for (int s = 0; s < 2; ++s) {
    bf16x8 af = *(const bf16x8*)&ewb[(size_t)rowa * DE + s * 32 + lh * 8];
    #pragma unroll
    for (int tt = 0; tt < 2; ++tt) {
      int t = wave * 2 + tt;
      bf16x8 bf = *(const bf16x8*)&Wp3[((t * 2 + s) * 64 + lane) * 8];
      acc[tt] = __builtin_amdgcn_mfma_f32_16x16x32_bf16(af, bf, acc[tt], 0, 0, 0);
    }
  }
  #pragma unroll
  for (int tt = 0; tt < 2; ++tt) {
    int c = (wave * 2 + tt) * 16 + l15;
    #pragma unroll
    for (int r = 0; r < 4; ++r) {
      int row = m0 + lh * 4 + r;
      if (row < nN) ewout[(size_t)row * 128 + c] = acc[tt][r];
    }
  }
}

// ---------- finalize: o = (vacc + ewout)/s + hr, LN, ReLU -> ynorm (no atomics) ----------
__global__ __launch_bounds__(256) void k_fin(const float* __restrict__ sden,
                                             const float* __restrict__ vaccf,
                                             const float* __restrict__ ewout,
                                             const ushort* __restrict__ hrb,
                                             const float* __restrict__ gamma,
                                             const float* __restrict__ beta,
                                             float* __restrict__ ynorm, int nN) {
  int lane = threadIdx.x & 63, grp = lane >> 5, l5 = lane & 31;
  int n = blockIdx.x * 8 + (threadIdx.x >> 6) * 2 + grp;
  if (n >= nN) return;
  float s = sden[n];
  float inv = (s > 0.f) ? 1.f / s : 0.f;
  float4 v4 = *(const float4*)&vaccf[(size_t)n * 128 + l5 * 4];
  float4 w4 = *(const float4*)&ewout[(size_t)n * 128 + l5 * 4];
  ushort4 hv = *(const ushort4*)&hrb[(size_t)n * 128 + l5 * 4];
  float4 o4;
  o4.x = (v4.x + w4.x) * inv + bf2f(hv.x);
  o4.y = (v4.y + w4.y) * inv + bf2f(hv.y);
  o4.z = (v4.z + w4.z) * inv + bf2f(hv.z);
  o4.w = (v4.w + w4.w) * inv + bf2f(hv.w);
  float s1 = o4.x + o4.y + o4.z + o4.w;
  float sq = o4.x*o4.x + o4.y*o4.y + o4.z*o4.z + o4.w*o4.w;
  #pragma unroll
  for (int off = 1; off < 32; off <<= 1) {
    s1 += __shfl_xor(s1, off);
    sq += __shfl_xor(sq, off);
  }
  float mu = s1 * (1.f / 128.f);
  float var = sq * (1.f / 128.f) - mu * mu;
  float rstd = rsqrtf(var + 1e-5f);
  float4 g4 = *(const float4*)&gamma[l5 * 4];
  float4 b4 = *(const float4*)&beta[l5 * 4];
  float4 y;
  y.x = fmaxf((o4.x - mu) * rstd * g4.x + b4.x, 0.f);
  y.y = fmaxf((o4.y - mu) * rstd * g4.y + b4.y, 0.f);
  y.z = fmaxf((o4.z - mu) * rstd * g4.z + b4.z, 0.f);
  y.w = fmaxf((o4.w - mu) * rstd * g4.w + b4.w, 0.f);
  *(float4*)&ynorm[(size_t)n * 128 + l5 * 4] = y;
}

// ---------- segmented mean pool: one block per graph, contiguous node range ----------
__global__ __launch_bounds__(128) void k_pool(const float* __restrict__ ynorm,
                                              const int* __restrict__ gstart,
                                              float* __restrict__ out) {
  int b = blockIdx.x, t = threadIdx.x;
  int beg = gstart[b], end = gstart[b + 1];
  float a0 = 0.f, a1 = 0.f, a2 = 0.f, a3 = 0.f;
  int n = beg;
  for (; n + 4 <= end; n += 4) {
    a0 += ynorm[(size_t)(n + 0) * 128 + t];
    a1 += ynorm[(size_t)(n + 1) * 128 + t];
    a2 += ynorm[(size_t)(n + 2) * 128 + t];
    a3 += ynorm[(size_t)(n + 3) * 128 + t];
  }
  for (; n < end; ++n) a0 += ynorm[(size_t)n * 128 + t];
  float acc = (a0 + a1) + (a2 + a3);
  out[b * 128 + t] = acc / fmaxf((float)(end - beg), 1.f);
}

extern "C" void kernel_launch(void* const* d_in, const int* in_sizes, int n_in,
                              void* d_out, int out_size, void* d_ws, size_t ws_size,
                              hipStream_t stream) {
  const float* x         = (const float*)d_in[0];
  const float* edge_attr = (const float*)d_in[1];
  const int*   edge_index= (const int*)d_in[2];
  const int*   batch     = (const int*)d_in[3];
  const float* W1 = (const float*)d_in[4];
  const float* b1 = (const float*)d_in[5];
  const float* Wq = (const float*)d_in[6];  const float* bq = (const float*)d_in[7];
  const float* Wk = (const float*)d_in[8];  const float* bk = (const float*)d_in[9];
  const float* Wv = (const float*)d_in[10]; const float* bv = (const float*)d_in[11];
  const float* We = (const float*)d_in[12]; const float* be = (const float*)d_in[13];
  const float* Wr = (const float*)d_in[14]; const float* br = (const float*)d_in[15];
  const float* gamma = (const float*)d_in[16];
  const float* beta  = (const float*)d_in[17];
  float* out = (float*)d_out;

  const int nN = in_sizes[0] / DN;       // 50000
  const int nE = in_sizes[1] / DE;       // 1600000
  const int B  = out_size / DEMB;        // 64

  char* p = (char*)d_ws;
  auto alloc = [&](size_t bytes) -> void* {
    void* r = (void*)p;
    p += (bytes + 255) & ~(size_t)255;
    return r;
  };
  // ---- zeroed region ----
  int*   degi   = (int*)  alloc((size_t)nN * 4);
  int*   cursor = (int*)  alloc((size_t)nN * 4);
  size_t zero_bytes = (size_t)(p - (char*)d_ws);
  // ---- non-zeroed ----
  int*    row_ptr = (int*)   alloc((size_t)(nN + 1) * 4);
  int*    gstart  = (int*)   alloc((size_t)(B + 1) * 4);
  float*  dinv    = (float*) alloc((size_t)nN * 4);
  int2*   csr_se  = (int2*)  alloc((size_t)nE * 8);
  ushort* Wp1     = (ushort*)alloc((size_t)16 * 4 * 64 * 8 * 2);
  ushort* Wp2     = (ushort*)alloc((size_t)36 * 8 * 64 * 8 * 2);
  ushort* Wp3     = (ushort*)alloc((size_t)8 * 2 * 64 * 8 * 2);
  float*  bcat    = (float*) alloc(576 * 4);
  ushort* qwb     = (ushort*)alloc((size_t)nN * 192 * 2);
  ushort* hrb     = (ushort*)alloc((size_t)nN * 128 * 2);
  ushort* hb      = (ushort*)alloc((size_t)nN * DHID * 2);
  ushort* xwsb    = (ushort*)alloc((size_t)nN * DHID * 2);  // aliased: xws, then kb|vb
  ushort* kb      = xwsb;                 // xws dead after k_gcnE; gemm2 writes kb/vb here
  ushort* vb      = xwsb + (size_t)nN * 128;
  float*  sden    = (float*) alloc((size_t)nN * 4);
  float*  vaccf   = (float*) alloc((size_t)nN * 128 * 4);
  ushort* ewb     = (ushort*)alloc((size_t)nN * DE * 2);
  float*  ewout   = (float*) alloc((size_t)nN * 128 * 4);
  float*  ynorm   = (float*) alloc((size_t)nN * 128 * 4);
  size_t required = (size_t)(p - (char*)d_ws);
  if (ws_size < required) return;

  hipMemsetAsync(d_ws, 0, zero_bytes, stream);

  k_prep1<<<128, 256, 0, stream>>>(W1, Wp1);
  k_prep2<<<576, 256, 0, stream>>>(Wq, Wk, Wv, Wr, We, Wp2);
  k_prep_b<<<3, 256, 0, stream>>>(bq, bk, bv, br, be, We, bcat);
  k_prep3<<<32, 256, 0, stream>>>(We, Wp3);
  k_deg<<<(nE + 255) / 256, 256, 0, stream>>>(edge_index, degi, nE);
  k_dinv<<<(nN + 255) / 256, 256, 0, stream>>>(degi, dinv, nN);
  k_scan<<<1, 1024, 0, stream>>>(degi, row_ptr, nN);
  k_scatter<<<(nE + 255) / 256, 256, 0, stream>>>(edge_index, row_ptr, cursor,
                                                  csr_se, nE);
  k_gbounds<<<(nN + 255) / 256, 256, 0, stream>>>(batch, gstart, nN, B);
  k_gemm1<<<(nN + 15) / 16, 256, 0, stream>>>(x, Wp1, dinv, xwsb, nN);
  k_gcnE<<<(nN + 3) / 4, 256, 0, stream>>>(xwsb, csr_se, row_ptr, dinv, b1, hb, nN);
  k_gemm2<<<(nN + 15) / 16, 256, 0, stream>>>(hb, Wp2, bcat, qwb, kb, vb, hrb, nN);
  k_edge<<<(nN + 3) / 4, 256, 0, stream>>>(qwb, kb, vb, edge_attr, csr_se, row_ptr,
                                           sden, vaccf, ewb, nN);
  k_ewe<<<(nN + 15) / 16, 256, 0, stream>>>(ewb, Wp3, ewout, nN);
  k_fin<<<(nN + 7) / 8, 256, 0, stream>>>(sden, vaccf, ewout, hrb, gamma, beta,
                                          ynorm, nN);
  k_pool<<<B, 128, 0, stream>>>(ynorm, gstart, out);
}

// Round 11
// 661.178 us; speedup vs baseline: 3.4012x; 1.0296x over previous
//
#include <hip/hip_runtime.h>

typedef short bf16x8 __attribute__((ext_vector_type(8)));
typedef float f32x4 __attribute__((ext_vector_type(4)));

#define DN 128
#define DE 64
#define DEMB 128
#define DHID 256
#define SCALE 0.08838834764831845f  // 1/sqrt(128)

__device__ __forceinline__ ushort f2bf(float f) {
  unsigned u = __float_as_uint(f);
  return (ushort)((u + 0x7FFFu + ((u >> 16) & 1u)) >> 16);  // RNE
}
__device__ __forceinline__ float bf2f(ushort u) {
  return __uint_as_float((unsigned)u << 16);
}

// ---------- weight pack for GEMM1: W1[128][256] -> frag order, bf16 ----------
__global__ void k_prep1(const float* __restrict__ W1, ushort* __restrict__ Wp1) {
  int idx = blockIdx.x * 256 + threadIdx.x;
  if (idx >= 16 * 4 * 64 * 8) return;
  int j = idx & 7, lane = (idx >> 3) & 63, s = (idx >> 9) & 3, t = idx >> 11;
  int k = s * 32 + (lane >> 4) * 8 + j;
  int c = t * 16 + (lane & 15);
  Wp1[idx] = f2bf(W1[k * DHID + c]);
}

// ---------- weight pack for GEMM2: Wcat[256][576] = [Wq*s | Wk | Wv | Wr | (Wq@We^T)*s] ----------
__global__ void k_prep2(const float* __restrict__ Wq, const float* __restrict__ Wk,
                        const float* __restrict__ Wv, const float* __restrict__ Wr,
                        const float* __restrict__ We, ushort* __restrict__ Wp2) {
  int idx = blockIdx.x * 256 + threadIdx.x;
  if (idx >= 36 * 8 * 64 * 8) return;
  int j = idx & 7, lane = (idx >> 3) & 63, s = (idx >> 9) & 7, t = idx >> 12;
  int k = s * 32 + (lane >> 4) * 8 + j;
  int c = t * 16 + (lane & 15);
  float v;
  if (c < 128)       v = Wq[k * DEMB + c] * SCALE;
  else if (c < 256)  v = Wk[k * DEMB + (c - 128)];
  else if (c < 384)  v = Wv[k * DEMB + (c - 256)];
  else if (c < 512)  v = Wr[k * DEMB + (c - 384)];
  else {
    int cc = c - 512;
    float a = 0.f;
    for (int u = 0; u < DEMB; ++u) a += Wq[k * DEMB + u] * We[cc * DEMB + u];
    v = a * SCALE;
  }
  Wp2[idx] = f2bf(v);
}

__global__ void k_prep_b(const float* __restrict__ bq, const float* __restrict__ bk,
                         const float* __restrict__ bv, const float* __restrict__ br,
                         const float* __restrict__ be, const float* __restrict__ We,
                         float* __restrict__ bcat) {
  int j = blockIdx.x * 256 + threadIdx.x;
  if (j >= 576) return;
  float v;
  if (j < 128)       v = bq[j] * SCALE;
  else if (j < 256)  v = bk[j - 128] + be[j - 128];
  else if (j < 384)  v = bv[j - 256] + be[j - 256];
  else if (j < 512)  v = br[j - 384];
  else {
    int cc = j - 512;
    float a = 0.f;
    for (int u = 0; u < DEMB; ++u) a += bq[u] * We[cc * DEMB + u];
    v = a * SCALE;
  }
  bcat[j] = v;
}

// ---------- weight pack for EWE GEMM: We[64][128] -> frag order, bf16 ----------
__global__ void k_prep3(const float* __restrict__ We, ushort* __restrict__ Wp3) {
  int idx = blockIdx.x * 256 + threadIdx.x;
  if (idx >= 8 * 2 * 64 * 8) return;
  int j = idx & 7, lane = (idx >> 3) & 63, s = (idx >> 9) & 1, t = idx >> 10;
  int k = s * 32 + (lane >> 4) * 8 + j;
  int c = t * 16 + (lane & 15);
  Wp3[idx] = f2bf(We[k * DEMB + c]);
}

// ---------- CSR build ----------
__global__ void k_deg(const int* __restrict__ ei, int* __restrict__ degi, int nE) {
  int e = blockIdx.x * 256 + threadIdx.x;
  if (e < nE) atomicAdd(&degi[ei[nE + e]], 1);
}

__global__ void k_dinv(const int* __restrict__ degi, float* __restrict__ dinv, int nN) {
  int n = blockIdx.x * 256 + threadIdx.x;
  if (n < nN) dinv[n] = rsqrtf(1.0f + (float)degi[n]);
}

__global__ __launch_bounds__(1024) void k_scan(const int* __restrict__ degi,
                                               int* __restrict__ row_ptr, int n) {
  __shared__ int wsum[16];
  __shared__ int carry_s;
  int lane = threadIdx.x & 63, wid = threadIdx.x >> 6;
  if (threadIdx.x == 0) carry_s = 0;
  __syncthreads();
  for (int base = 0; base < n; base += 1024) {
    int i = base + threadIdx.x;
    int v = (i < n) ? degi[i] : 0;
    int sc = v;
    #pragma unroll
    for (int off = 1; off < 64; off <<= 1) {
      int t = __shfl_up(sc, off);
      if (lane >= off) sc += t;
    }
    if (lane == 63) wsum[wid] = sc;
    int carry0 = carry_s;
    __syncthreads();
    if (wid == 0) {
      int w = (lane < 16) ? wsum[lane] : 0;
      int swc = w;
      #pragma unroll
      for (int off = 1; off < 16; off <<= 1) {
        int t = __shfl_up(swc, off);
        if (lane >= off) swc += t;
      }
      if (lane < 16) wsum[lane] = swc - w;
      if (lane == 15) carry_s = carry0 + swc;
    }
    __syncthreads();
    if (i < n) row_ptr[i] = carry0 + wsum[wid] + sc - v;
    __syncthreads();
  }
  if (threadIdx.x == 0) row_ptr[n] = carry_s;
}

__global__ void k_scatter(const int* __restrict__ ei, const int* __restrict__ row_ptr,
                          int* __restrict__ cursor, int2* __restrict__ csr_se, int nE) {
  int e = blockIdx.x * 256 + threadIdx.x;
  if (e >= nE) return;
  int dst = ei[nE + e];
  int pos = row_ptr[dst] + atomicAdd(&cursor[dst], 1);
  csr_se[pos] = make_int2(ei[e], e);
}

// ---------- graph segment boundaries from sorted batch ----------
__global__ void k_gbounds(const int* __restrict__ batch, int* __restrict__ gstart,
                          int nN, int B) {
  int n = blockIdx.x * 256 + threadIdx.x;
  if (n >= nN) return;
  int b = batch[n];
  if (n == 0) {
    for (int g = 0; g <= b; ++g) gstart[g] = 0;
  } else {
    int pb = batch[n - 1];
    for (int g = pb + 1; g <= b; ++g) gstart[g] = n;
  }
  if (n == nN - 1) {
    for (int g = b + 1; g <= B; ++g) gstart[g] = nN;
  }
}

// ---------- cast x to bf16 with per-row dinv scale: xsb[n][128] = bf16(dinv[n]*x[n]) ----------
__global__ __launch_bounds__(256) void k_xcast(const float* __restrict__ x,
                                               const float* __restrict__ dinv,
                                               ushort* __restrict__ xsb, int nN) {
  int idx = blockIdx.x * 256 + threadIdx.x;     // one thread = 4 dims
  if (idx >= nN * 32) return;
  int n = idx >> 5, q = idx & 31;
  float dn = dinv[n];
  float4 v = *(const float4*)&x[(size_t)n * DN + q * 4];
  ushort4 o;
  o.x = f2bf(v.x * dn); o.y = f2bf(v.y * dn);
  o.z = f2bf(v.z * dn); o.w = f2bf(v.w * dn);
  *(ushort4*)&xsb[(size_t)n * DN + q * 4] = o;
}

// ---------- GCN aggregate in 128-dim input space: wave/node, group/edge, 256 B/edge ----------
__global__ __launch_bounds__(256) void k_gcnX(const ushort* __restrict__ xsb,
                                              const int2* __restrict__ csr_se,
                                              const int* __restrict__ row_ptr,
                                              const float* __restrict__ dinv,
                                              ushort* __restrict__ aggxb, int nN) {
  int lane = threadIdx.x & 63;
  int n = blockIdx.x * 4 + (threadIdx.x >> 6);
  if (n >= nN) return;
  int grp = lane >> 4, l15 = lane & 15;
  int beg = row_ptr[n], end = row_ptr[n + 1];
  float acc[8] = {};
  for (int i0 = beg; i0 < end; i0 += 16) {
    #pragma unroll
    for (int u = 0; u < 4; ++u) {
      int e = i0 + u * 4 + grp;
      bool val = e < end;
      int cl = val ? e : end - 1;
      int src = csr_se[cl].x;                    // same addr across group: HW broadcast
      uint4 xa = *(const uint4*)&xsb[(size_t)src * DN + l15 * 8];
      float w = val ? 1.f : 0.f;
      unsigned qq[4] = {xa.x, xa.y, xa.z, xa.w};
      #pragma unroll
      for (int d = 0; d < 4; ++d) {
        acc[2*d]   = fmaf(w, __uint_as_float(qq[d] << 16), acc[2*d]);
        acc[2*d+1] = fmaf(w, __uint_as_float(qq[d] & 0xFFFF0000u), acc[2*d+1]);
      }
    }
  }
  #pragma unroll
  for (int d = 0; d < 8; ++d) {
    acc[d] += __shfl_xor(acc[d], 16);
    acc[d] += __shfl_xor(acc[d], 32);
  }
  if (grp == 0) {
    uint4 sa = *(const uint4*)&xsb[(size_t)n * DN + l15 * 8];
    unsigned sq[4] = {sa.x, sa.y, sa.z, sa.w};
    float dn = dinv[n];
    ushort o[8];
    #pragma unroll
    for (int d = 0; d < 4; ++d) {
      float lo = __uint_as_float(sq[d] << 16);
      float hi = __uint_as_float(sq[d] & 0xFFFF0000u);
      o[2*d]   = f2bf(dn * (acc[2*d]   + lo));
      o[2*d+1] = f2bf(dn * (acc[2*d+1] + hi));
    }
    uint4 ov = {(unsigned)o[0] | ((unsigned)o[1] << 16),
                (unsigned)o[2] | ((unsigned)o[3] << 16),
                (unsigned)o[4] | ((unsigned)o[5] << 16),
                (unsigned)o[6] | ((unsigned)o[7] << 16)};
    *(uint4*)&aggxb[(size_t)n * DN + l15 * 8] = ov;
  }
}

// ---------- GEMM1b (MFMA bf16): hb[n][256] = relu(aggxb[n][128] @ W1 + b1) ----------
__global__ __launch_bounds__(256) void k_gemm1b(const ushort* __restrict__ aggxb,
                                                const ushort* __restrict__ Wp1,
                                                const float* __restrict__ b1,
                                                ushort* __restrict__ hb, int nN) {
  int lane = threadIdx.x & 63, wave = threadIdx.x >> 6;
  int l15 = lane & 15, lh = lane >> 4;
  int m0 = blockIdx.x * 16;
  int rowa = m0 + l15; if (rowa >= nN) rowa = nN - 1;
  f32x4 acc[4] = {};
  #pragma unroll
  for (int s = 0; s < 4; ++s) {
    bf16x8 af = *(const bf16x8*)&aggxb[(size_t)rowa * DN + s * 32 + lh * 8];
    #pragma unroll
    for (int tt = 0; tt < 4; ++tt) {
      int t = wave * 4 + tt;
      bf16x8 bf = *(const bf16x8*)&Wp1[((t * 4 + s) * 64 + lane) * 8];
      acc[tt] = __builtin_amdgcn_mfma_f32_16x16x32_bf16(af, bf, acc[tt], 0, 0, 0);
    }
  }
  #pragma unroll
  for (int tt = 0; tt < 4; ++tt) {
    int c = (wave * 4 + tt) * 16 + l15;
    float bc = b1[c];
    #pragma unroll
    for (int r = 0; r < 4; ++r) {
      int row = m0 + lh * 4 + r;
      if (row < nN) hb[(size_t)row * DHID + c] = f2bf(fmaxf(acc[tt][r] + bc, 0.f));
    }
  }
}

// ---------- GEMM2 (MFMA bf16): emits qwb[192]=[q*s|wqe*s], kb[128], vb[128], hrb[128] ----------
__global__ __launch_bounds__(256) void k_gemm2(const ushort* __restrict__ hb,
                                               const ushort* __restrict__ Wp2,
                                               const float* __restrict__ bcat,
                                               ushort* __restrict__ qwb,
                                               ushort* __restrict__ kb,
                                               ushort* __restrict__ vb,
                                               ushort* __restrict__ hrb, int nN) {
  int lane = threadIdx.x & 63, wave = threadIdx.x >> 6;
  int l15 = lane & 15, lh = lane >> 4;
  int m0 = blockIdx.x * 16;
  int rowa = m0 + l15; if (rowa >= nN) rowa = nN - 1;
  f32x4 acc[9] = {};
  for (int s = 0; s < 8; ++s) {
    bf16x8 af = *(const bf16x8*)&hb[(size_t)rowa * DHID + s * 32 + lh * 8];
    #pragma unroll
    for (int tt = 0; tt < 9; ++tt) {
      int t = wave * 9 + tt;
      bf16x8 bf = *(const bf16x8*)&Wp2[((t * 8 + s) * 64 + lane) * 8];
      acc[tt] = __builtin_amdgcn_mfma_f32_16x16x32_bf16(af, bf, acc[tt], 0, 0, 0);
    }
  }
  #pragma unroll
  for (int tt = 0; tt < 9; ++tt) {
    int c = (wave * 9 + tt) * 16 + l15;
    float bc = bcat[c];
    #pragma unroll
    for (int r = 0; r < 4; ++r) {
      int row = m0 + lh * 4 + r;
      if (row >= nN) continue;
      ushort val = f2bf(acc[tt][r] + bc);
      if (c < 128)      qwb[(size_t)row * 192 + c] = val;
      else if (c < 256) kb[(size_t)row * 128 + (c - 128)] = val;
      else if (c < 384) vb[(size_t)row * 128 + (c - 256)] = val;
      else if (c < 512) hrb[(size_t)row * 128 + (c - 384)] = val;
      else              qwb[(size_t)row * 192 + 128 + (c - 512)] = val;
    }
  }
}

// ---------- fused attention edge pass: wave per node, group per edge, 4-deep ----------
__global__ __launch_bounds__(256) void k_edge(const ushort* __restrict__ qwb,
                                              const ushort* __restrict__ kb,
                                              const ushort* __restrict__ vb,
                                              const float* __restrict__ ea32,
                                              const int2* __restrict__ csr_se,
                                              const int* __restrict__ row_ptr,
                                              float* __restrict__ sden,
                                              float* __restrict__ vaccf,
                                              ushort* __restrict__ ewb, int nN) {
  int lane = threadIdx.x & 63;
  int n = blockIdx.x * 4 + (threadIdx.x >> 6);
  if (n >= nN) return;
  int grp = lane >> 4, l15 = lane & 15;
  const ushort* qp = &qwb[(size_t)n * 192];
  bf16x8 qv = *(const bf16x8*)&qp[l15 * 8];         // q dims l15*8..+7 (pre-scaled)
  ushort4 wv = *(const ushort4*)&qp[128 + l15 * 4]; // wqe dims l15*4..+3 (pre-scaled)
  float q[8];
  #pragma unroll
  for (int d = 0; d < 8; ++d) q[d] = bf2f((ushort)qv[d]);
  float w0 = bf2f(wv.x), w1 = bf2f(wv.y), w2 = bf2f(wv.z), w3 = bf2f(wv.w);
  float s_acc = 0.f;
  float av[8] = {};
  float ae[4] = {};
  int beg = row_ptr[n], end = row_ptr[n + 1];
  for (int i0 = beg; i0 < end; i0 += 16) {
    int2 se[4]; bool vl[4];
    #pragma unroll
    for (int u = 0; u < 4; ++u) {
      int e = i0 + u * 4 + grp;
      vl[u] = e < end;
      se[u] = csr_se[vl[u] ? e : end - 1];        // same addr across group: HW broadcast
    }
    bf16x8 kv8[4]; bf16x8 vv8[4]; float4 eav[4];
    #pragma unroll
    for (int u = 0; u < 4; ++u) {
      kv8[u] = *(const bf16x8*)&kb[(size_t)se[u].x * 128 + l15 * 8];
      vv8[u] = *(const bf16x8*)&vb[(size_t)se[u].x * 128 + l15 * 8];
      eav[u] = *(const float4*)&ea32[(size_t)se[u].y * DE + l15 * 4];
    }
    #pragma unroll
    for (int u = 0; u < 4; ++u) {
      float dot = w0 * eav[u].x + w1 * eav[u].y + w2 * eav[u].z + w3 * eav[u].w;
      #pragma unroll
      for (int d = 0; d < 8; ++d) dot = fmaf(q[d], bf2f((ushort)kv8[u][d]), dot);
      dot += __shfl_xor(dot, 1);
      dot += __shfl_xor(dot, 2);
      dot += __shfl_xor(dot, 4);
      dot += __shfl_xor(dot, 8);                  // 16-lane group reduce
      float p = vl[u] ? __expf(dot) : 0.f;        // no-max softmax (shift-invariant)
      s_acc += p;
      #pragma unroll
      for (int d = 0; d < 8; ++d) av[d] = fmaf(p, bf2f((ushort)vv8[u][d]), av[d]);
      ae[0] = fmaf(p, eav[u].x, ae[0]);
      ae[1] = fmaf(p, eav[u].y, ae[1]);
      ae[2] = fmaf(p, eav[u].z, ae[2]);
      ae[3] = fmaf(p, eav[u].w, ae[3]);
    }
  }
  s_acc += __shfl_xor(s_acc, 16); s_acc += __shfl_xor(s_acc, 32);
  #pragma unroll
  for (int d = 0; d < 8; ++d) {
    av[d] += __shfl_xor(av[d], 16);
    av[d] += __shfl_xor(av[d], 32);
  }
  #pragma unroll
  for (int d = 0; d < 4; ++d) {
    ae[d] += __shfl_xor(ae[d], 16);
    ae[d] += __shfl_xor(ae[d], 32);
  }
  if (grp == 0) {
    if (l15 == 0) sden[n] = s_acc;
    float4 o0 = {av[0], av[1], av[2], av[3]};
    float4 o1 = {av[4], av[5], av[6], av[7]};
    float* vr = &vaccf[(size_t)n * 128 + l15 * 8];
    *(float4*)vr = o0;
    *(float4*)(vr + 4) = o1;
    ushort4 eo;
    eo.x = f2bf(ae[0]); eo.y = f2bf(ae[1]); eo.z = f2bf(ae[2]); eo.w = f2bf(ae[3]);
    *(ushort4*)&ewb[(size_t)n * DE + l15 * 4] = eo;
  }
}

// ---------- EWE GEMM (MFMA bf16): ewout[nN,128] = ewb[nN,64] @ We[64,128] ----------
__global__ __launch_bounds__(256) void k_ewe(const ushort* __restrict__ ewb,
                                             const ushort* __restrict__ Wp3,
                                             float* __restrict__ ewout, int nN) {
  int lane = threadIdx.x & 63, wave = threadIdx.x >> 6;
  int l15 = lane & 15, lh = lane >> 4;
  int m0 = blockIdx.x * 16;
  int rowa = m0 + l15; if (rowa >= nN) rowa = nN - 1;
  f32x4 acc[2] = {};
  #pragma unroll
  for (int s = 0; s < 2; ++s) {
    bf16x8 af = *(const bf16x8*)&ewb[(size_t)rowa * DE + s * 32 + lh * 8];
    #pragma unroll
    for (int tt = 0; tt < 2; ++tt) {
      int t = wave * 2 + tt;
      bf16x8 bf = *(const bf16x8*)&Wp3[((t * 2 + s) * 64 + lane) * 8];
      acc[tt] = __builtin_amdgcn_mfma_f32_16x16x32_bf16(af, bf, acc[tt], 0, 0, 0);
    }
  }
  #pragma unroll
  for (int tt = 0; tt < 2; ++tt) {
    int c = (wave * 2 + tt) * 16 + l15;
    #pragma unroll
    for (int r = 0; r < 4; ++r) {
      int row = m0 + lh * 4 + r;
      if (row < nN) ewout[(size_t)row * 128 + c] = acc[tt][r];
    }
  }
}

// ---------- finalize: o = (vacc + ewout)/s + hr, LN, ReLU -> ynorm (no atomics) ----------
__global__ __launch_bounds__(256) void k_fin(const float* __restrict__ sden,
                                             const float* __restrict__ vaccf,
                                             const float* __restrict__ ewout,
                                             const ushort* __restrict__ hrb,
                                             const float* __restrict__ gamma,
                                             const float* __restrict__ beta,
                                             float* __restrict__ ynorm, int nN) {
  int lane = threadIdx.x & 63, grp = lane >> 5, l5 = lane & 31;
  int n = blockIdx.x * 8 + (threadIdx.x >> 6) * 2 + grp;
  if (n >= nN) return;
  float s = sden[n];
  float inv = (s > 0.f) ? 1.f / s : 0.f;
  float4 v4 = *(const float4*)&vaccf[(size_t)n * 128 + l5 * 4];
  float4 w4 = *(const float4*)&ewout[(size_t)n * 128 + l5 * 4];
  ushort4 hv = *(const ushort4*)&hrb[(size_t)n * 128 + l5 * 4];
  float4 o4;
  o4.x = (v4.x + w4.x) * inv + bf2f(hv.x);
  o4.y = (v4.y + w4.y) * inv + bf2f(hv.y);
  o4.z = (v4.z + w4.z) * inv + bf2f(hv.z);
  o4.w = (v4.w + w4.w) * inv + bf2f(hv.w);
  float s1 = o4.x + o4.y + o4.z + o4.w;
  float sq = o4.x*o4.x + o4.y*o4.y + o4.z*o4.z + o4.w*o4.w;
  #pragma unroll
  for (int off = 1; off < 32; off <<= 1) {
    s1 += __shfl_xor(s1, off);
    sq += __shfl_xor(sq, off);
  }
  float mu = s1 * (1.f / 128.f);
  float var = sq * (1.f / 128.f) - mu * mu;
  float rstd = rsqrtf(var + 1e-5f);
  float4 g4 = *(const float4*)&gamma[l5 * 4];
  float4 b4 = *(const float4*)&beta[l5 * 4];
  float4 y;
  y.x = fmaxf((o4.x - mu) * rstd * g4.x + b4.x, 0.f);
  y.y = fmaxf((o4.y - mu) * rstd * g4.y + b4.y, 0.f);
  y.z = fmaxf((o4.z - mu) * rstd * g4.z + b4.z, 0.f);
  y.w = fmaxf((o4.w - mu) * rstd * g4.w + b4.w, 0.f);
  *(float4*)&ynorm[(size_t)n * 128 + l5 * 4] = y;
}

// ---------- segmented mean pool: one block per graph, contiguous node range ----------
__global__ __launch_bounds__(128) void k_pool(const float* __restrict__ ynorm,
                                              const int* __restrict__ gstart,
                                              float* __restrict__ out) {
  int b = blockIdx.x, t = threadIdx.x;
  int beg = gstart[b], end = gstart[b + 1];
  float a0 = 0.f, a1 = 0.f, a2 = 0.f, a3 = 0.f;
  int n = beg;
  for (; n + 4 <= end; n += 4) {
    a0 += ynorm[(size_t)(n + 0) * 128 + t];
    a1 += ynorm[(size_t)(n + 1) * 128 + t];
    a2 += ynorm[(size_t)(n + 2) * 128 + t];
    a3 += ynorm[(size_t)(n + 3) * 128 + t];
  }
  for (; n < end; ++n) a0 += ynorm[(size_t)n * 128 + t];
  float acc = (a0 + a1) + (a2 + a3);
  out[b * 128 + t] = acc / fmaxf((float)(end - beg), 1.f);
}

extern "C" void kernel_launch(void* const* d_in, const int* in_sizes, int n_in,
                              void* d_out, int out_size, void* d_ws, size_t ws_size,
                              hipStream_t stream) {
  const float* x         = (const float*)d_in[0];
  const float* edge_attr = (const float*)d_in[1];
  const int*   edge_index= (const int*)d_in[2];
  const int*   batch     = (const int*)d_in[3];
  const float* W1 = (const float*)d_in[4];
  const float* b1 = (const float*)d_in[5];
  const float* Wq = (const float*)d_in[6];  const float* bq = (const float*)d_in[7];
  const float* Wk = (const float*)d_in[8];  const float* bk = (const float*)d_in[9];
  const float* Wv = (const float*)d_in[10]; const float* bv = (const float*)d_in[11];
  const float* We = (const float*)d_in[12]; const float* be = (const float*)d_in[13];
  const float* Wr = (const float*)d_in[14]; const float* br = (const float*)d_in[15];
  const float* gamma = (const float*)d_in[16];
  const float* beta  = (const float*)d_in[17];
  float* out = (float*)d_out;

  const int nN = in_sizes[0] / DN;       // 50000
  const int nE = in_sizes[1] / DE;       // 1600000
  const int B  = out_size / DEMB;        // 64

  char* p = (char*)d_ws;
  auto alloc = [&](size_t bytes) -> void* {
    void* r = (void*)p;
    p += (bytes + 255) & ~(size_t)255;
    return r;
  };
  // ---- zeroed region ----
  int*   degi   = (int*)  alloc((size_t)nN * 4);
  int*   cursor = (int*)  alloc((size_t)nN * 4);
  size_t zero_bytes = (size_t)(p - (char*)d_ws);
  // ---- non-zeroed ----
  int*    row_ptr = (int*)   alloc((size_t)(nN + 1) * 4);
  int*    gstart  = (int*)   alloc((size_t)(B + 1) * 4);
  float*  dinv    = (float*) alloc((size_t)nN * 4);
  int2*   csr_se  = (int2*)  alloc((size_t)nE * 8);
  ushort* Wp1     = (ushort*)alloc((size_t)16 * 4 * 64 * 8 * 2);
  ushort* Wp2     = (ushort*)alloc((size_t)36 * 8 * 64 * 8 * 2);
  ushort* Wp3     = (ushort*)alloc((size_t)8 * 2 * 64 * 8 * 2);
  float*  bcat    = (float*) alloc(576 * 4);
  ushort* qwb     = (ushort*)alloc((size_t)nN * 192 * 2);
  ushort* hrb     = (ushort*)alloc((size_t)nN * 128 * 2);
  ushort* hb      = (ushort*)alloc((size_t)nN * DHID * 2);
  // xsb/aggxb dead after gemm1b; gemm2 reuses their space for kb/vb
  ushort* xsb     = (ushort*)alloc((size_t)nN * DN * 2);
  ushort* aggxb   = (ushort*)alloc((size_t)nN * DN * 2);
  ushort* kb      = xsb;     // xsb dead after k_gcnX
  ushort* vb      = aggxb;   // aggxb dead after k_gemm1b
  float*  sden    = (float*) alloc((size_t)nN * 4);
  float*  vaccf   = (float*) alloc((size_t)nN * 128 * 4);
  ushort* ewb     = (ushort*)alloc((size_t)nN * DE * 2);
  float*  ewout   = (float*) alloc((size_t)nN * 128 * 4);
  float*  ynorm   = (float*) alloc((size_t)nN * 128 * 4);
  size_t required = (size_t)(p - (char*)d_ws);
  if (ws_size < required) return;

  hipMemsetAsync(d_ws, 0, zero_bytes, stream);

  k_prep1<<<128, 256, 0, stream>>>(W1, Wp1);
  k_prep2<<<576, 256, 0, stream>>>(Wq, Wk, Wv, Wr, We, Wp2);
  k_prep_b<<<3, 256, 0, stream>>>(bq, bk, bv, br, be, We, bcat);
  k_prep3<<<32, 256, 0, stream>>>(We, Wp3);
  k_deg<<<(nE + 255) / 256, 256, 0, stream>>>(edge_index, degi, nE);
  k_dinv<<<(nN + 255) / 256, 256, 0, stream>>>(degi, dinv, nN);
  k_scan<<<1, 1024, 0, stream>>>(degi, row_ptr, nN);
  k_scatter<<<(nE + 255) / 256, 256, 0, stream>>>(edge_index, row_ptr, cursor,
                                                  csr_se, nE);
  k_gbounds<<<(nN + 255) / 256, 256, 0, stream>>>(batch, gstart, nN, B);
  k_xcast<<<(nN * 32 + 255) / 256, 256, 0, stream>>>(x, dinv, xsb, nN);
  k_gcnX<<<(nN + 3) / 4, 256, 0, stream>>>(xsb, csr_se, row_ptr, dinv, aggxb, nN);
  k_gemm1b<<<(nN + 15) / 16, 256, 0, stream>>>(aggxb, Wp1, b1, hb, nN);
  k_gemm2<<<(nN + 15) / 16, 256, 0, stream>>>(hb, Wp2, bcat, qwb, kb, vb, hrb, nN);
  k_edge<<<(nN + 3) / 4, 256, 0, stream>>>(qwb, kb, vb, edge_attr, csr_se, row_ptr,
                                           sden, vaccf, ewb, nN);
  k_ewe<<<(nN + 15) / 16, 256, 0, stream>>>(ewb, Wp3, ewout, nN);
  k_fin<<<(nN + 7) / 8, 256, 0, stream>>>(sden, vaccf, ewout, hrb, gamma, beta,
                                          ynorm, nN);
  k_pool<<<B, 128, 0, stream>>>(ynorm, gstart, out);
}